// Round 6
// baseline (339.864 us; speedup 1.0000x reference)
//
#include <hip/hip_runtime.h>

#define BATCH 131072

typedef __attribute__((ext_vector_type(8))) __bf16 bf16x8;
typedef __attribute__((ext_vector_type(16))) float f32x16;

__constant__ int FOFF[23] = {0,4,8,12,16,20,24,28,32,36,40,44,48,50,52,53,57,58,59,60,61,62,63};
__constant__ int FDIM[23] = {4,4,4,4,4,4,4,4,4,4,4,4,2,2,1,4,1,1,1,1,1,1,2};

__device__ __forceinline__ unsigned short f2bf(float f){
  unsigned int u = __float_as_uint(f);
  u += 0x7fffu + ((u>>16)&1u);   // RNE
  return (unsigned short)(u>>16);
}
__device__ __forceinline__ unsigned int packpair(float a, float b){
  return (unsigned int)f2bf(a) | ((unsigned int)f2bf(b)<<16);
}
__device__ __forceinline__ float bflo(unsigned int u){ return __uint_as_float(u<<16); }
__device__ __forceinline__ float bfhi(unsigned int u){ return __uint_as_float(u & 0xffff0000u); }

// ---------------- prep: pack W1..W5 into MFMA-B fragment-linear bf16 layout ----------------
// layout: frag index = (ks*6 + nt)*64 + lane ; j in 0..7 within frag; value = W[k][n],
// k=ks*16+(lane>>5)*8+j, n=nt*32+(lane&31); zero-padded. W1: 15 ksteps; W2..5: 11. N 164->192.
__global__ void prep_weights(const float* __restrict__ W1, const float* __restrict__ W2,
    const float* __restrict__ W3, const float* __restrict__ W4, const float* __restrict__ W5,
    unsigned short* __restrict__ wpack){
  int idx = blockIdx.x*256 + threadIdx.x;
  if (idx >= 22656) return;
  const float* W; int rel; int Kd;
  if (idx < 5760){ W = W1; rel = idx; Kd = 230; }
  else {
    int r2 = idx - 5760;
    int li = r2 / 4224; rel = r2 - li*4224; Kd = 164;
    W = (li==0)?W2:((li==1)?W3:((li==2)?W4:W5));
  }
  int lane = rel & 63, rem = rel >> 6;
  int nt = rem % 6, ks = rem / 6;
  int n  = nt*32 + (lane&31);
  int k0 = ks*16 + ((lane>>5)<<3);
  unsigned int v[4];
  #pragma unroll
  for (int p=0;p<4;p++){
    int ka = k0 + 2*p, kb = ka+1;
    float fa = (ka<Kd && n<164) ? W[ka*164+n] : 0.f;
    float fb = (kb<Kd && n<164) ? W[kb*164+n] : 0.f;
    v[p] = packpair(fa, fb);
  }
  *(uint4*)(wpack + (size_t)idx*8) = make_uint4(v[0],v[1],v[2],v[3]);
}

// ---------------- attention chunk: C (<=2) query rows of one sample, h-pitch 64 ----------------
// Runtime C + if(c<C) guards. This exact body fits a 64-VGPR allocation WITHOUT spill when
// compiled in a 1024-thread kernel (proven R5). Do NOT template C / drop guards (R2: 261 MB
// spill). 64 VGPR is mandatory: it is the 8-waves/SIMD budget enabling 2 blocks/CU.
__device__ __forceinline__ void attn_chunk2(int s, int ibase, int C,
    const unsigned int* hp, const float* sw, unsigned int* z32){
  // ---- g = h_i * M (M = Wq Wk^T / sqrt(10), broadcast reads from LDS) ----
  float g[2][10];
  #pragma unroll
  for (int c=0;c<2;c++)
    #pragma unroll
    for (int d=0;d<10;d++) g[c][d]=0.f;
  {
    float hi[2][10];
    #pragma unroll
    for (int c=0;c<2;c++) if (c<C){
      #pragma unroll
      for (int p=0;p<5;p++){
        unsigned int u = hp[((ibase+c)*5+p)*64 + s];
        hi[c][2*p] = bflo(u); hi[c][2*p+1] = bfhi(u);
      }
    }
    #pragma unroll
    for (int e=0;e<10;e++){
      float m[10];
      #pragma unroll
      for (int d=0;d<10;d++) m[d] = sw[1840 + e*12 + d];
      #pragma unroll
      for (int c=0;c<2;c++) if (c<C){
        float he = hi[c][e];
        #pragma unroll
        for (int d=0;d<10;d++) g[c][d] += he*m[d];
      }
    }
  }
  // ---- single-pass unnormalized softmax over 23 keys ----
  float st[2][10]; float tau[2];
  #pragma unroll
  for (int c=0;c<2;c++){
    tau[c]=0.f;
    #pragma unroll
    for (int d=0;d<10;d++) st[c][d]=0.f;
  }
  for (int j=0;j<23;j++){
    float hj[10];
    #pragma unroll
    for (int p=0;p<5;p++){
      unsigned int u = hp[(j*5+p)*64 + s];
      hj[2*p]=bflo(u); hj[2*p+1]=bfhi(u);
    }
    #pragma unroll
    for (int c=0;c<2;c++) if (c<C){
      float l = 0.f;
      #pragma unroll
      for (int d=0;d<10;d++) l += g[c][d]*hj[d];
      float e = __expf(l);
      tau[c] += e;
      #pragma unroll
      for (int d=0;d<10;d++) st[c][d] += e*hj[d];
    }
  }
  #pragma unroll
  for (int c=0;c<2;c++) if (c<C){
    float inv = 1.f/tau[c];
    #pragma unroll
    for (int d=0;d<10;d++) st[c][d] *= inv;
  }
  // ---- ctx = st * Wv (Wv broadcast from LDS, shared across the C rows) ----
  float ct[2][10];
  #pragma unroll
  for (int c=0;c<2;c++)
    #pragma unroll
    for (int d=0;d<10;d++) ct[c][d]=0.f;
  #pragma unroll
  for (int e=0;e<10;e++){
    float wv[10];
    #pragma unroll
    for (int d=0;d<10;d++) wv[d] = sw[1960 + e*12 + d];
    #pragma unroll
    for (int c=0;c<2;c++) if (c<C){
      float se = st[c][e];
      #pragma unroll
      for (int d=0;d<10;d++) ct[c][d] += se*wv[d];
    }
  }
  // ---- residual + pack to z ----
  #pragma unroll
  for (int c=0;c<2;c++) if (c<C){
    int i = ibase+c;
    #pragma unroll
    for (int p=0;p<5;p++){
      unsigned int u = hp[(i*5+p)*64 + s];
      float z0 = bflo(u) + ct[c][2*p];
      float z1 = bfhi(u) + ct[c][2*p+1];
      z32[s*124 + i*5 + p] = packpair(z0,z1);
    }
  }
}

// ---------------- MFMA MLP inner: NT n-tiles for one 32-row M-tile ----------------
template<int KSTEPS, int NT>
__device__ __forceinline__ void mlp_tiles(const unsigned short* abase, const bf16x8* wb,
    const float* __restrict__ bias, unsigned short* out16, int nt0, int colb, int rowb){
  f32x16 acc[NT];
  #pragma unroll
  for (int nt=0; nt<NT; ++nt)
    #pragma unroll
    for (int r=0;r<16;r++) acc[nt][r]=0.f;
  #pragma unroll
  for (int ks=0; ks<KSTEPS; ++ks){
    bf16x8 a = *(const bf16x8*)(abase + ks*16);
    const bf16x8* wk = wb + ks*(6*64);
    #pragma unroll
    for (int nt=0; nt<NT; ++nt)
      acc[nt] = __builtin_amdgcn_mfma_f32_32x32x16_bf16(a, wk[nt*64], acc[nt], 0,0,0);
  }
  #pragma unroll
  for (int nt=0; nt<NT; ++nt){
    int n = (nt0+nt)*32 + colb;
    float b = (n<164) ? bias[n] : 0.f;
    #pragma unroll
    for (int r=0;r<16;r++){
      int row = rowb + (r&3) + 8*(r>>2);
      float v = fmaxf(acc[nt][r] + b, 0.f);
      out16[row*200 + n] = f2bf(v);
    }
  }
}

// 64 rows, 16 waves: 2 M-tiles x 6 N-tiles at NT=1 (12 active waves, 4 idle; MFMA is ~2% of time)
template<int KSTEPS>
__device__ __forceinline__ void mlp_layer(const unsigned short* in16, int inPitch,
    const bf16x8* __restrict__ wp, const float* __restrict__ bias,
    unsigned short* out16, int t){
  const int lane = t & 63;
  const int w = t >> 6;      // 0..15
  const int mt = w & 1;      // 2 M-tiles of 32
  const int nt = w >> 1;     // 0..7; only 0..5 carry tiles (N 164->192)
  if (nt >= 6) return;
  const unsigned short* abase = in16 + (mt*32 + (lane&31))*inPitch + ((lane>>5)<<3);
  const int colb = lane&31;
  const int rowb = mt*32 + 4*(lane>>5);
  mlp_tiles<KSTEPS,1>(abase, wp + nt*64 + lane, bias, out16, nt, colb, rowb);
}

// ---------------- fused main kernel: 64 samples / 1024-thread workgroup, 2 blocks/CU ----------------
// 32 waves/CU: two independent 16-wave blocks co-resident (LDS 2x71,680 = 143 KB < 160 KB;
// VGPR 64 = 512/8 budget, proven spill-free for this body at 1024-thread compile in R5).
// One block's barriers/MFMA overlap the other's VALU attention (m114 pipe co-scheduling).
__global__ __launch_bounds__(1024, 8) void actor_main(
    const float* __restrict__ xg, const float* __restrict__ Wproj, const float* __restrict__ bproj,
    const float* __restrict__ Wq, const float* __restrict__ Wk, const float* __restrict__ Wv,
    const float* __restrict__ b1, const float* __restrict__ b2, const float* __restrict__ b3,
    const float* __restrict__ b4, const float* __restrict__ b5,
    const float* __restrict__ Wmove, const float* __restrict__ bmove,
    const float* __restrict__ Wmark, const float* __restrict__ bmark,
    const unsigned short* __restrict__ wpack, float* __restrict__ out)
{
  // LDS: [0,31744) z-buffer (64 x pitch 248 bf16) / x-stage union;
  //      [31744,61184) h SoA pairs (23*5*64 u32) / act buffer (64 x pitch 200 bf16);
  //      [61184,71472) small weights. Total 71,472 B.
  __shared__ __align__(16) unsigned char LDS[71472];
  float* xb = (float*)LDS;
  unsigned int* z32 = (unsigned int*)LDS;
  unsigned short* z16 = (unsigned short*)LDS;
  unsigned int* hp = (unsigned int*)(LDS + 31744);
  unsigned short* a16 = (unsigned short*)(LDS + 31744);
  float* sw = (float*)(LDS + 61184);
  unsigned int* swu = (unsigned int*)(LDS + 61184);

  const int t = threadIdx.x;
  const int S0 = blockIdx.x*64;

  // ---- P0: stage x (vectorized, coalesced) + pad zeros + small weights ----
  {
    const float4* src4 = (const float4*)(xg + (size_t)S0*65);
    float4* x4 = (float4*)xb;
    for (int i=t; i<1040; i+=1024) x4[i] = src4[i];   // 64*65 = 4160 floats
    if (t<8) xb[4160+t] = 0.f;   // proj over-read pad (zero-weight lanes)
  }
  for (int idx=t; idx<2572; idx+=1024){
    if (idx < 1840){                 // proj packed: [o][0..3]=w, [4]=bias
      int o = idx>>3, u = idx&7;
      int fi = o/10;
      float v = 0.f;
      if (u<4){ if (u < FDIM[fi]) v = Wproj[(FOFF[fi]+u)*230 + o]; }
      else if (u==4) v = bproj[o];
      sw[idx] = v;
    } else if (idx < 1960){          // M = Wq*Wk^T/sqrt(10), [10][12]
      int r = idx-1840, e = r/12, d = r-12*e;
      float v = 0.f;
      if (d<10){ float ssum=0.f;
        #pragma unroll
        for (int k2=0;k2<10;k2++) ssum += Wq[e*10+k2]*Wk[d*10+k2];
        v = ssum*0.31622776601683794f; }
      sw[idx] = v;
    } else if (idx < 2080){          // Wv [10][12]
      int r = idx-1960, e = r/12, d = r-12*e;
      sw[idx] = (d<10)? Wv[e*10+d] : 0.f;
    } else {                         // head weights, bf16 pairs [6][82]
      int r = idx-2080, o = r/82, kp = r-82*o;
      float w0, w1;
      if (o<5){ w0 = Wmove[(2*kp)*5+o]; w1 = Wmove[(2*kp+1)*5+o]; }
      else    { w0 = Wmark[2*kp];       w1 = Wmark[2*kp+1]; }
      swu[idx] = packpair(w0,w1);
    }
  }
  __syncthreads();

  // ---- P1: block-diagonal projection -> h SoA bf16 pairs hp[(j*5+p)*64+s] ----
  for (int L=t; L<7360; L+=1024){
    int s = L & 63, jp = L>>6;
    int j = jp/5, p = jp-5*j;
    int o0 = j*10 + 2*p;
    int roff = FOFF[j];
    float a0 = sw[o0*8+4], a1 = sw[o0*8+12];
    #pragma unroll
    for (int u=0;u<4;u++){
      float xv = xb[s*65 + roff + u];
      a0 += xv * sw[o0*8+u];
      a1 += xv * sw[o0*8+8+u];
    }
    hp[L] = packpair(a0,a1);
  }
  __syncthreads();

  // ---- P2: attention (16 waves; waves 0-6 take 2 rows each, waves 7-15 one row each) ----
  {
    const int s = t & 63;
    const int q = t >> 6;            // 0..15, exactly one wave per q
    if (q < 7){
      attn_chunk2(s, 2*q, 2, hp, sw, z32);     // rows 0..13
    } else {
      attn_chunk2(s, q+7, 1, hp, sw, z32);     // rows 14..22
    }
    __builtin_amdgcn_sched_barrier(0);
    if (q == 15){
      // lightest wave zeroes z pad cols 230..239 (K padded to 240 for layer1)
      for (int idx=s; idx<320; idx+=64){
        int ss = idx/5, pc = idx-5*ss;
        z32[ss*124 + 115+pc] = 0u;
      }
    }
  }
  __syncthreads();

  // ---- P3: MLP, 5 layers of MFMA, ping-pong LDS act buffers ----
  const bf16x8* wpk = (const bf16x8*)wpack;
  mlp_layer<15>(z16, 248, wpk,          b1, a16, t); __syncthreads();
  mlp_layer<11>(a16, 200, wpk + 5760,   b2, z16, t); __syncthreads();
  mlp_layer<11>(z16, 200, wpk + 9984,   b3, a16, t); __syncthreads();
  mlp_layer<11>(a16, 200, wpk + 14208,  b4, z16, t); __syncthreads();
  mlp_layer<11>(z16, 200, wpk + 18432,  b5, a16, t); __syncthreads();

  // ---- P4: heads (move[5] + mark[1]) ----
  if (t < 384){
    int s2 = t & 63, o = t>>6;
    const unsigned int* ar = (const unsigned int*)(a16 + s2*200);
    const unsigned int* wr = swu + 2080 + o*82;
    float acc = 0.f;
    for (int kp=0; kp<82; ++kp){
      unsigned int ua = ar[kp], uw = wr[kp];
      acc += bflo(ua)*bflo(uw) + bfhi(ua)*bfhi(uw);
    }
    acc += (o<5)? bmove[o] : bmark[0];
    if (o<5) out[(size_t)(S0+s2)*5 + o] = acc;
    else     out[(size_t)BATCH*5 + S0 + s2] = acc;
  }
}

extern "C" void kernel_launch(void* const* d_in, const int* in_sizes, int n_in,
                              void* d_out, int out_size, void* d_ws, size_t ws_size,
                              hipStream_t stream){
  (void)in_sizes; (void)n_in; (void)out_size; (void)ws_size;
  const float* x     = (const float*)d_in[0];
  const float* Wproj = (const float*)d_in[1];
  const float* bproj = (const float*)d_in[2];
  const float* Wq    = (const float*)d_in[3];
  const float* Wk    = (const float*)d_in[4];
  const float* Wv    = (const float*)d_in[5];
  const float* W1    = (const float*)d_in[6];
  const float* b1    = (const float*)d_in[7];
  const float* W2    = (const float*)d_in[8];
  const float* b2    = (const float*)d_in[9];
  const float* W3    = (const float*)d_in[10];
  const float* b3    = (const float*)d_in[11];
  const float* W4    = (const float*)d_in[12];
  const float* b4    = (const float*)d_in[13];
  const float* W5    = (const float*)d_in[14];
  const float* b5    = (const float*)d_in[15];
  const float* Wmove = (const float*)d_in[16];
  const float* bmove = (const float*)d_in[17];
  const float* Wmark = (const float*)d_in[18];
  const float* bmark = (const float*)d_in[19];
  unsigned short* wpack = (unsigned short*)d_ws;

  prep_weights<<<89, 256, 0, stream>>>(W1, W2, W3, W4, W5, wpack);
  actor_main<<<2048, 1024, 0, stream>>>(x, Wproj, bproj, Wq, Wk, Wv,
      b1, b2, b3, b4, b5, Wmove, bmove, Wmark, bmark, wpack, (float*)d_out);
}

// Round 7
// 312.342 us; speedup vs baseline: 1.0881x; 1.0881x over previous
//
#include <hip/hip_runtime.h>

#define BATCH 131072

typedef __attribute__((ext_vector_type(8))) __bf16 bf16x8;
typedef __attribute__((ext_vector_type(16))) float f32x16;

__constant__ int FOFF[23] = {0,4,8,12,16,20,24,28,32,36,40,44,48,50,52,53,57,58,59,60,61,62,63};
__constant__ int FDIM[23] = {4,4,4,4,4,4,4,4,4,4,4,4,2,2,1,4,1,1,1,1,1,1,2};

__device__ __forceinline__ unsigned short f2bf(float f){
  unsigned int u = __float_as_uint(f);
  u += 0x7fffu + ((u>>16)&1u);   // RNE
  return (unsigned short)(u>>16);
}
__device__ __forceinline__ unsigned int packpair(float a, float b){
  return (unsigned int)f2bf(a) | ((unsigned int)f2bf(b)<<16);
}
__device__ __forceinline__ float bflo(unsigned int u){ return __uint_as_float(u<<16); }
__device__ __forceinline__ float bfhi(unsigned int u){ return __uint_as_float(u & 0xffff0000u); }

// ---------------- prep: pack W1..W5 into MFMA-B fragment-linear bf16 layout ----------------
// layout: frag index = (ks*6 + nt)*64 + lane ; j in 0..7 within frag; value = W[k][n],
// k=ks*16+(lane>>5)*8+j, n=nt*32+(lane&31); zero-padded. W1: 15 ksteps; W2..5: 11. N 164->192.
__global__ void prep_weights(const float* __restrict__ W1, const float* __restrict__ W2,
    const float* __restrict__ W3, const float* __restrict__ W4, const float* __restrict__ W5,
    unsigned short* __restrict__ wpack){
  int idx = blockIdx.x*256 + threadIdx.x;
  if (idx >= 22656) return;
  const float* W; int rel; int Kd;
  if (idx < 5760){ W = W1; rel = idx; Kd = 230; }
  else {
    int r2 = idx - 5760;
    int li = r2 / 4224; rel = r2 - li*4224; Kd = 164;
    W = (li==0)?W2:((li==1)?W3:((li==2)?W4:W5));
  }
  int lane = rel & 63, rem = rel >> 6;
  int nt = rem % 6, ks = rem / 6;
  int n  = nt*32 + (lane&31);
  int k0 = ks*16 + ((lane>>5)<<3);
  unsigned int v[4];
  #pragma unroll
  for (int p=0;p<4;p++){
    int ka = k0 + 2*p, kb = ka+1;
    float fa = (ka<Kd && n<164) ? W[ka*164+n] : 0.f;
    float fb = (kb<Kd && n<164) ? W[kb*164+n] : 0.f;
    v[p] = packpair(fa, fb);
  }
  *(uint4*)(wpack + (size_t)idx*8) = make_uint4(v[0],v[1],v[2],v[3]);
}

// ---------------- attention chunk: C (<=2) query rows of one sample, h-pitch 64 ----------------
// Runtime C + if(c<C) guards. This exact body fits a 64-VGPR allocation WITHOUT spill when
// compiled in a 1024-thread kernel (proven R5: VGPR_Count=64, WRITE_SIZE=3MB). Do NOT
// template C / drop guards (R2: 261 MB spill). Do NOT let the cap drop to 32 (R6: 305 MB).
__device__ __forceinline__ void attn_chunk2(int s, int ibase, int C,
    const unsigned int* hp, const float* sw, unsigned int* z32){
  // ---- g = h_i * M (M = Wq Wk^T / sqrt(10), broadcast reads from LDS) ----
  float g[2][10];
  #pragma unroll
  for (int c=0;c<2;c++)
    #pragma unroll
    for (int d=0;d<10;d++) g[c][d]=0.f;
  {
    float hi[2][10];
    #pragma unroll
    for (int c=0;c<2;c++) if (c<C){
      #pragma unroll
      for (int p=0;p<5;p++){
        unsigned int u = hp[((ibase+c)*5+p)*64 + s];
        hi[c][2*p] = bflo(u); hi[c][2*p+1] = bfhi(u);
      }
    }
    #pragma unroll
    for (int e=0;e<10;e++){
      float m[10];
      #pragma unroll
      for (int d=0;d<10;d++) m[d] = sw[1840 + e*12 + d];
      #pragma unroll
      for (int c=0;c<2;c++) if (c<C){
        float he = hi[c][e];
        #pragma unroll
        for (int d=0;d<10;d++) g[c][d] += he*m[d];
      }
    }
  }
  // ---- single-pass unnormalized softmax over 23 keys ----
  float st[2][10]; float tau[2];
  #pragma unroll
  for (int c=0;c<2;c++){
    tau[c]=0.f;
    #pragma unroll
    for (int d=0;d<10;d++) st[c][d]=0.f;
  }
  for (int j=0;j<23;j++){
    float hj[10];
    #pragma unroll
    for (int p=0;p<5;p++){
      unsigned int u = hp[(j*5+p)*64 + s];
      hj[2*p]=bflo(u); hj[2*p+1]=bfhi(u);
    }
    #pragma unroll
    for (int c=0;c<2;c++) if (c<C){
      float l = 0.f;
      #pragma unroll
      for (int d=0;d<10;d++) l += g[c][d]*hj[d];
      float e = __expf(l);
      tau[c] += e;
      #pragma unroll
      for (int d=0;d<10;d++) st[c][d] += e*hj[d];
    }
  }
  #pragma unroll
  for (int c=0;c<2;c++) if (c<C){
    float inv = 1.f/tau[c];
    #pragma unroll
    for (int d=0;d<10;d++) st[c][d] *= inv;
  }
  // ---- ctx = st * Wv (Wv broadcast from LDS, shared across the C rows) ----
  float ct[2][10];
  #pragma unroll
  for (int c=0;c<2;c++)
    #pragma unroll
    for (int d=0;d<10;d++) ct[c][d]=0.f;
  #pragma unroll
  for (int e=0;e<10;e++){
    float wv[10];
    #pragma unroll
    for (int d=0;d<10;d++) wv[d] = sw[1960 + e*12 + d];
    #pragma unroll
    for (int c=0;c<2;c++) if (c<C){
      float se = st[c][e];
      #pragma unroll
      for (int d=0;d<10;d++) ct[c][d] += se*wv[d];
    }
  }
  // ---- residual + pack to z ----
  #pragma unroll
  for (int c=0;c<2;c++) if (c<C){
    int i = ibase+c;
    #pragma unroll
    for (int p=0;p<5;p++){
      unsigned int u = hp[(i*5+p)*64 + s];
      float z0 = bflo(u) + ct[c][2*p];
      float z1 = bfhi(u) + ct[c][2*p+1];
      z32[s*124 + i*5 + p] = packpair(z0,z1);
    }
  }
}

// ---------------- MFMA MLP inner: NT n-tiles for one 32-row M-tile ----------------
template<int KSTEPS, int NT>
__device__ __forceinline__ void mlp_tiles(const unsigned short* abase, const bf16x8* wb,
    const float* __restrict__ bias, unsigned short* out16, int nt0, int colb, int rowb){
  f32x16 acc[NT];
  #pragma unroll
  for (int nt=0; nt<NT; ++nt)
    #pragma unroll
    for (int r=0;r<16;r++) acc[nt][r]=0.f;
  #pragma unroll
  for (int ks=0; ks<KSTEPS; ++ks){
    bf16x8 a = *(const bf16x8*)(abase + ks*16);
    const bf16x8* wk = wb + ks*(6*64);
    #pragma unroll
    for (int nt=0; nt<NT; ++nt)
      acc[nt] = __builtin_amdgcn_mfma_f32_32x32x16_bf16(a, wk[nt*64], acc[nt], 0,0,0);
  }
  #pragma unroll
  for (int nt=0; nt<NT; ++nt){
    int n = (nt0+nt)*32 + colb;
    float b = (n<164) ? bias[n] : 0.f;
    #pragma unroll
    for (int r=0;r<16;r++){
      int row = rowb + (r&3) + 8*(r>>2);
      float v = fmaxf(acc[nt][r] + b, 0.f);
      out16[row*200 + n] = f2bf(v);
    }
  }
}

// 64 rows, 16 waves: 2 M-tiles x 6 N-tiles at NT=1 (12 active waves, 4 idle; MFMA is ~2% of time)
template<int KSTEPS>
__device__ __forceinline__ void mlp_layer(const unsigned short* in16, int inPitch,
    const bf16x8* __restrict__ wp, const float* __restrict__ bias,
    unsigned short* out16, int t){
  const int lane = t & 63;
  const int w = t >> 6;      // 0..15
  const int mt = w & 1;      // 2 M-tiles of 32
  const int nt = w >> 1;     // 0..7; only 0..5 carry tiles (N 164->192)
  if (nt >= 6) return;
  const unsigned short* abase = in16 + (mt*32 + (lane&31))*inPitch + ((lane>>5)<<3);
  const int colb = lane&31;
  const int rowb = mt*32 + 4*(lane>>5);
  mlp_tiles<KSTEPS,1>(abase, wp + nt*64 + lane, bias, out16, nt, colb, rowb);
}

// ---------------- fused main kernel: 64 samples / 1024-thread workgroup, 2 blocks/CU ----------------
// launch_bounds arg2 decoded empirically (R0-R6): compiler sizes the VGPR cap as if arg2 were
// BLOCKS/CU: (512,2)->128, (512,4)->64, (1024,8)->32. For two 16-wave blocks we need the
// 64-VGPR budget (8 waves/SIMD) => (1024, 2). R5 proved this body fits 64 VGPR spill-free.
// LDS 2x71,680 = 143 KB <= 160 KB; 32 waves = CU max.
__global__ __launch_bounds__(1024, 2) void actor_main(
    const float* __restrict__ xg, const float* __restrict__ Wproj, const float* __restrict__ bproj,
    const float* __restrict__ Wq, const float* __restrict__ Wk, const float* __restrict__ Wv,
    const float* __restrict__ b1, const float* __restrict__ b2, const float* __restrict__ b3,
    const float* __restrict__ b4, const float* __restrict__ b5,
    const float* __restrict__ Wmove, const float* __restrict__ bmove,
    const float* __restrict__ Wmark, const float* __restrict__ bmark,
    const unsigned short* __restrict__ wpack, float* __restrict__ out)
{
  // LDS: [0,31744) z-buffer (64 x pitch 248 bf16) / x-stage union;
  //      [31744,61184) h SoA pairs (23*5*64 u32) / act buffer (64 x pitch 200 bf16);
  //      [61184,71472) small weights. Total 71,472 B.
  __shared__ __align__(16) unsigned char LDS[71472];
  float* xb = (float*)LDS;
  unsigned int* z32 = (unsigned int*)LDS;
  unsigned short* z16 = (unsigned short*)LDS;
  unsigned int* hp = (unsigned int*)(LDS + 31744);
  unsigned short* a16 = (unsigned short*)(LDS + 31744);
  float* sw = (float*)(LDS + 61184);
  unsigned int* swu = (unsigned int*)(LDS + 61184);

  const int t = threadIdx.x;
  const int S0 = blockIdx.x*64;

  // ---- P0: stage x (vectorized, coalesced) + pad zeros + small weights ----
  {
    const float4* src4 = (const float4*)(xg + (size_t)S0*65);
    float4* x4 = (float4*)xb;
    for (int i=t; i<1040; i+=1024) x4[i] = src4[i];   // 64*65 = 4160 floats
    if (t<8) xb[4160+t] = 0.f;   // proj over-read pad (zero-weight lanes)
  }
  for (int idx=t; idx<2572; idx+=1024){
    if (idx < 1840){                 // proj packed: [o][0..3]=w, [4]=bias
      int o = idx>>3, u = idx&7;
      int fi = o/10;
      float v = 0.f;
      if (u<4){ if (u < FDIM[fi]) v = Wproj[(FOFF[fi]+u)*230 + o]; }
      else if (u==4) v = bproj[o];
      sw[idx] = v;
    } else if (idx < 1960){          // M = Wq*Wk^T/sqrt(10), [10][12]
      int r = idx-1840, e = r/12, d = r-12*e;
      float v = 0.f;
      if (d<10){ float ssum=0.f;
        #pragma unroll
        for (int k2=0;k2<10;k2++) ssum += Wq[e*10+k2]*Wk[d*10+k2];
        v = ssum*0.31622776601683794f; }
      sw[idx] = v;
    } else if (idx < 2080){          // Wv [10][12]
      int r = idx-1960, e = r/12, d = r-12*e;
      sw[idx] = (d<10)? Wv[e*10+d] : 0.f;
    } else {                         // head weights, bf16 pairs [6][82]
      int r = idx-2080, o = r/82, kp = r-82*o;
      float w0, w1;
      if (o<5){ w0 = Wmove[(2*kp)*5+o]; w1 = Wmove[(2*kp+1)*5+o]; }
      else    { w0 = Wmark[2*kp];       w1 = Wmark[2*kp+1]; }
      swu[idx] = packpair(w0,w1);
    }
  }
  __syncthreads();

  // ---- P1: block-diagonal projection -> h SoA bf16 pairs hp[(j*5+p)*64+s] ----
  for (int L=t; L<7360; L+=1024){
    int s = L & 63, jp = L>>6;
    int j = jp/5, p = jp-5*j;
    int o0 = j*10 + 2*p;
    int roff = FOFF[j];
    float a0 = sw[o0*8+4], a1 = sw[o0*8+12];
    #pragma unroll
    for (int u=0;u<4;u++){
      float xv = xb[s*65 + roff + u];
      a0 += xv * sw[o0*8+u];
      a1 += xv * sw[o0*8+8+u];
    }
    hp[L] = packpair(a0,a1);
  }
  __syncthreads();

  // ---- P2: attention (16 waves; waves 0-6 take 2 rows each, waves 7-15 one row each) ----
  {
    const int s = t & 63;
    const int q = t >> 6;            // 0..15, exactly one wave per q
    if (q < 7){
      attn_chunk2(s, 2*q, 2, hp, sw, z32);     // rows 0..13
    } else {
      attn_chunk2(s, q+7, 1, hp, sw, z32);     // rows 14..22
    }
    __builtin_amdgcn_sched_barrier(0);
    if (q == 15){
      // lightest wave zeroes z pad cols 230..239 (K padded to 240 for layer1)
      for (int idx=s; idx<320; idx+=64){
        int ss = idx/5, pc = idx-5*ss;
        z32[ss*124 + 115+pc] = 0u;
      }
    }
  }
  __syncthreads();

  // ---- P3: MLP, 5 layers of MFMA, ping-pong LDS act buffers ----
  const bf16x8* wpk = (const bf16x8*)wpack;
  mlp_layer<15>(z16, 248, wpk,          b1, a16, t); __syncthreads();
  mlp_layer<11>(a16, 200, wpk + 5760,   b2, z16, t); __syncthreads();
  mlp_layer<11>(z16, 200, wpk + 9984,   b3, a16, t); __syncthreads();
  mlp_layer<11>(a16, 200, wpk + 14208,  b4, z16, t); __syncthreads();
  mlp_layer<11>(z16, 200, wpk + 18432,  b5, a16, t); __syncthreads();

  // ---- P4: heads (move[5] + mark[1]) ----
  if (t < 384){
    int s2 = t & 63, o = t>>6;
    const unsigned int* ar = (const unsigned int*)(a16 + s2*200);
    const unsigned int* wr = swu + 2080 + o*82;
    float acc = 0.f;
    for (int kp=0; kp<82; ++kp){
      unsigned int ua = ar[kp], uw = wr[kp];
      acc += bflo(ua)*bflo(uw) + bfhi(ua)*bfhi(uw);
    }
    acc += (o<5)? bmove[o] : bmark[0];
    if (o<5) out[(size_t)(S0+s2)*5 + o] = acc;
    else     out[(size_t)BATCH*5 + S0 + s2] = acc;
  }
}

extern "C" void kernel_launch(void* const* d_in, const int* in_sizes, int n_in,
                              void* d_out, int out_size, void* d_ws, size_t ws_size,
                              hipStream_t stream){
  (void)in_sizes; (void)n_in; (void)out_size; (void)ws_size;
  const float* x     = (const float*)d_in[0];
  const float* Wproj = (const float*)d_in[1];
  const float* bproj = (const float*)d_in[2];
  const float* Wq    = (const float*)d_in[3];
  const float* Wk    = (const float*)d_in[4];
  const float* Wv    = (const float*)d_in[5];
  const float* W1    = (const float*)d_in[6];
  const float* b1    = (const float*)d_in[7];
  const float* W2    = (const float*)d_in[8];
  const float* b2    = (const float*)d_in[9];
  const float* W3    = (const float*)d_in[10];
  const float* b3    = (const float*)d_in[11];
  const float* W4    = (const float*)d_in[12];
  const float* b4    = (const float*)d_in[13];
  const float* W5    = (const float*)d_in[14];
  const float* b5    = (const float*)d_in[15];
  const float* Wmove = (const float*)d_in[16];
  const float* bmove = (const float*)d_in[17];
  const float* Wmark = (const float*)d_in[18];
  const float* bmark = (const float*)d_in[19];
  unsigned short* wpack = (unsigned short*)d_ws;

  prep_weights<<<89, 256, 0, stream>>>(W1, W2, W3, W4, W5, wpack);
  actor_main<<<2048, 1024, 0, stream>>>(x, Wproj, bproj, Wq, Wk, Wv,
      b1, b2, b3, b4, b5, Wmove, bmove, Wmark, bmark, wpack, (float*)d_out);
}

// Round 8
// 273.826 us; speedup vs baseline: 1.2412x; 1.1407x over previous
//
#include <hip/hip_runtime.h>

#define BATCH 131072

typedef __attribute__((ext_vector_type(8))) __bf16 bf16x8;
typedef __attribute__((ext_vector_type(16))) float f32x16;
typedef __attribute__((ext_vector_type(2))) float f32x2;

__constant__ int FOFF[23] = {0,4,8,12,16,20,24,28,32,36,40,44,48,50,52,53,57,58,59,60,61,62,63};
__constant__ int FDIM[23] = {4,4,4,4,4,4,4,4,4,4,4,4,2,2,1,4,1,1,1,1,1,1,2};

__device__ __forceinline__ unsigned short f2bf(float f){
  unsigned int u = __float_as_uint(f);
  u += 0x7fffu + ((u>>16)&1u);   // RNE
  return (unsigned short)(u>>16);
}
__device__ __forceinline__ unsigned int packpair(float a, float b){
  return (unsigned int)f2bf(a) | ((unsigned int)f2bf(b)<<16);
}
__device__ __forceinline__ float bflo(unsigned int u){ return __uint_as_float(u<<16); }
__device__ __forceinline__ float bfhi(unsigned int u){ return __uint_as_float(u & 0xffff0000u); }

// ---------------- prep: pack W1..W5 into MFMA-B fragment-linear bf16 layout ----------------
__global__ void prep_weights(const float* __restrict__ W1, const float* __restrict__ W2,
    const float* __restrict__ W3, const float* __restrict__ W4, const float* __restrict__ W5,
    unsigned short* __restrict__ wpack){
  int idx = blockIdx.x*256 + threadIdx.x;
  if (idx >= 22656) return;
  const float* W; int rel; int Kd;
  if (idx < 5760){ W = W1; rel = idx; Kd = 230; }
  else {
    int r2 = idx - 5760;
    int li = r2 / 4224; rel = r2 - li*4224; Kd = 164;
    W = (li==0)?W2:((li==1)?W3:((li==2)?W4:W5));
  }
  int lane = rel & 63, rem = rel >> 6;
  int nt = rem % 6, ks = rem / 6;
  int n  = nt*32 + (lane&31);
  int k0 = ks*16 + ((lane>>5)<<3);
  unsigned int v[4];
  #pragma unroll
  for (int p=0;p<4;p++){
    int ka = k0 + 2*p, kb = ka+1;
    float fa = (ka<Kd && n<164) ? W[ka*164+n] : 0.f;
    float fb = (kb<Kd && n<164) ? W[kb*164+n] : 0.f;
    v[p] = packpair(fa, fb);
  }
  *(uint4*)(wpack + (size_t)idx*8) = make_uint4(v[0],v[1],v[2],v[3]);
}

// ---------------- prep: small-weights image (once, instead of per-block scattered loads) ----
// word layout: [0,1840) proj packed f32 ([o][0..3]=w,[4]=bias,pad8); [1840,1960) M=WqWk^T/sqrt(10)
// [10][12] f32; [1960,2080) Wv [10][12] f32; [2080,2572) head bf16 pairs [6][82].
__global__ void prep_small(const float* __restrict__ Wproj, const float* __restrict__ bproj,
    const float* __restrict__ Wq, const float* __restrict__ Wk, const float* __restrict__ Wv,
    const float* __restrict__ Wmove, const float* __restrict__ Wmark,
    unsigned int* __restrict__ swimg){
  int idx = blockIdx.x*256 + threadIdx.x;
  if (idx >= 2572) return;
  unsigned int outv;
  if (idx < 1840){
    int o = idx>>3, u = idx&7;
    int fi = o/10;
    float v = 0.f;
    if (u<4){ if (u < FDIM[fi]) v = Wproj[(FOFF[fi]+u)*230 + o]; }
    else if (u==4) v = bproj[o];
    outv = __float_as_uint(v);
  } else if (idx < 1960){
    int r = idx-1840, e = r/12, d = r-12*e;
    float v = 0.f;
    if (d<10){ float ssum=0.f;
      #pragma unroll
      for (int k2=0;k2<10;k2++) ssum += Wq[e*10+k2]*Wk[d*10+k2];
      v = ssum*0.31622776601683794f; }
    outv = __float_as_uint(v);
  } else if (idx < 2080){
    int r = idx-1960, e = r/12, d = r-12*e;
    outv = __float_as_uint((d<10)? Wv[e*10+d] : 0.f);
  } else {
    int r = idx-2080, o = r/82, kp = r-82*o;
    float w0, w1;
    if (o<5){ w0 = Wmove[(2*kp)*5+o]; w1 = Wmove[(2*kp+1)*5+o]; }
    else    { w0 = Wmark[2*kp];       w1 = Wmark[2*kp+1]; }
    outv = packpair(w0,w1);
  }
  swimg[idx] = outv;
}

// ---------------- attention chunk: C (<=2) query rows, h stored as f32 pairs in LDS ----------
// All math in f32x2 so the compiler emits v_pk_fma_f32 (packed f32 = 2x scalar rate); h kept
// f32 in LDS so the j-loop has ZERO bf16 unpack ops. Runtime C + if(c<C) guards (R2 lesson:
// templating C lets the scheduler merge chunk live-ranges -> spill).
__device__ __forceinline__ void attn_chunk2(int s, int ibase, int C,
    const f32x2* hf2, const f32x2* swf2, unsigned int* z32){
  // ---- g = h_i * M (M broadcast from LDS as f32x2) ----
  f32x2 g2[2][5];
  #pragma unroll
  for (int c=0;c<2;c++)
    #pragma unroll
    for (int p=0;p<5;p++) g2[c][p] = (f32x2){0.f,0.f};
  {
    f32x2 hi2[2][5];
    #pragma unroll
    for (int c=0;c<2;c++) if (c<C){
      #pragma unroll
      for (int p=0;p<5;p++) hi2[c][p] = hf2[((ibase+c)*5+p)*64 + s];
    }
    #pragma unroll
    for (int e=0;e<10;e++){
      f32x2 m2[5];
      #pragma unroll
      for (int p=0;p<5;p++) m2[p] = swf2[920 + e*6 + p];
      #pragma unroll
      for (int c=0;c<2;c++) if (c<C){
        float he = (e&1) ? hi2[c][e>>1].y : hi2[c][e>>1].x;
        #pragma unroll
        for (int p=0;p<5;p++) g2[c][p] += m2[p]*he;
      }
    }
  }
  // ---- single-pass unnormalized softmax over 23 keys ----
  f32x2 st2[2][5]; float tau[2];
  #pragma unroll
  for (int c=0;c<2;c++){
    tau[c]=0.f;
    #pragma unroll
    for (int p=0;p<5;p++) st2[c][p] = (f32x2){0.f,0.f};
  }
  for (int j=0;j<23;j++){
    f32x2 hj2[5];
    #pragma unroll
    for (int p=0;p<5;p++) hj2[p] = hf2[(j*5+p)*64 + s];
    #pragma unroll
    for (int c=0;c<2;c++) if (c<C){
      f32x2 l2 = g2[c][0]*hj2[0];
      #pragma unroll
      for (int p=1;p<5;p++) l2 += g2[c][p]*hj2[p];
      float e = __expf(l2.x + l2.y);
      tau[c] += e;
      #pragma unroll
      for (int p=0;p<5;p++) st2[c][p] += hj2[p]*e;
    }
  }
  #pragma unroll
  for (int c=0;c<2;c++) if (c<C){
    float inv = 1.f/tau[c];
    #pragma unroll
    for (int p=0;p<5;p++) st2[c][p] *= inv;
  }
  // ---- ctx = st * Wv (Wv broadcast from LDS) ----
  f32x2 ct2[2][5];
  #pragma unroll
  for (int c=0;c<2;c++)
    #pragma unroll
    for (int p=0;p<5;p++) ct2[c][p] = (f32x2){0.f,0.f};
  #pragma unroll
  for (int e=0;e<10;e++){
    f32x2 wv2[5];
    #pragma unroll
    for (int p=0;p<5;p++) wv2[p] = swf2[980 + e*6 + p];
    #pragma unroll
    for (int c=0;c<2;c++) if (c<C){
      float se = (e&1) ? st2[c][e>>1].y : st2[c][e>>1].x;
      #pragma unroll
      for (int p=0;p<5;p++) ct2[c][p] += wv2[p]*se;
    }
  }
  // ---- residual + pack to z (v_cvt_pk_bf16_f32: 1 inst, RNE) ----
  #pragma unroll
  for (int c=0;c<2;c++) if (c<C){
    int i = ibase+c;
    #pragma unroll
    for (int p=0;p<5;p++){
      f32x2 h = hf2[(i*5+p)*64 + s];
      float z0 = h.x + ct2[c][p].x;
      float z1 = h.y + ct2[c][p].y;
      unsigned int r;
      asm volatile("v_cvt_pk_bf16_f32 %0, %1, %2" : "=v"(r) : "v"(z0), "v"(z1));
      z32[s*124 + i*5 + p] = r;
    }
  }
}

// ---------------- MFMA MLP inner: NT n-tiles for one 32-row M-tile ----------------
template<int KSTEPS, int NT>
__device__ __forceinline__ void mlp_tiles(const unsigned short* abase, const bf16x8* wb,
    const float* __restrict__ bias, unsigned short* out16, int nt0, int colb, int rowb){
  f32x16 acc[NT];
  #pragma unroll
  for (int nt=0; nt<NT; ++nt)
    #pragma unroll
    for (int r=0;r<16;r++) acc[nt][r]=0.f;
  #pragma unroll
  for (int ks=0; ks<KSTEPS; ++ks){
    bf16x8 a = *(const bf16x8*)(abase + ks*16);
    const bf16x8* wk = wb + ks*(6*64);
    #pragma unroll
    for (int nt=0; nt<NT; ++nt)
      acc[nt] = __builtin_amdgcn_mfma_f32_32x32x16_bf16(a, wk[nt*64], acc[nt], 0,0,0);
  }
  #pragma unroll
  for (int nt=0; nt<NT; ++nt){
    int n = (nt0+nt)*32 + colb;
    float b = (n<164) ? bias[n] : 0.f;
    #pragma unroll
    for (int r=0;r<16;r++){
      int row = rowb + (r&3) + 8*(r>>2);
      float v = fmaxf(acc[nt][r] + b, 0.f);
      out16[row*200 + n] = f2bf(v);
    }
  }
}

// 64 rows, 16 waves: 2 M-tiles x 6 N-tiles at NT=1 (12 active waves; MFMA ~2% of time)
template<int KSTEPS>
__device__ __forceinline__ void mlp_layer(const unsigned short* in16, int inPitch,
    const bf16x8* __restrict__ wp, const float* __restrict__ bias,
    unsigned short* out16, int t){
  const int lane = t & 63;
  const int w = t >> 6;      // 0..15
  const int mt = w & 1;      // 2 M-tiles of 32
  const int nt = w >> 1;     // 0..7; only 0..5 carry tiles (N 164->192)
  if (nt >= 6) return;
  const unsigned short* abase = in16 + (mt*32 + (lane&31))*inPitch + ((lane>>5)<<3);
  const int colb = lane&31;
  const int rowb = mt*32 + 4*(lane>>5);
  mlp_tiles<KSTEPS,1>(abase, wp + nt*64 + lane, bias, out16, nt, colb, rowb);
}

// ---------------- fused main kernel: 64 samples / 1024-thread workgroup ----------------
// 1 block/CU (16 waves) is the residency ceiling: unified regfile (VGPR+AGPR) needs ~80 regs
// (attention ~60 arch + 16 MFMA acc) and 2x16-wave blocks would require <=64 unified, which
// this kernel cannot meet without spill (R1/R4/R6: 0.2-2.9 GB scratch). So optimize per-wave
// VALU throughput instead: f32 h in LDS (no unpack) + packed f32x2 math (v_pk_fma_f32).
__global__ __launch_bounds__(1024, 1) void actor_main(
    const float* __restrict__ xg,
    const float* __restrict__ b1, const float* __restrict__ b2, const float* __restrict__ b3,
    const float* __restrict__ b4, const float* __restrict__ b5,
    const float* __restrict__ bmove, const float* __restrict__ bmark,
    const unsigned short* __restrict__ wpack, float* __restrict__ out)
{
  // LDS: [0,31744) z-buffer (64 x pitch 248 bf16) / x-stage union;
  //      [31744,90624) h f32-pair SoA (23*5*64 f32x2) / act buffer union (64 x pitch 200 bf16);
  //      [90624,100912) small-weights image. Total 100,912 B -> 1 workgroup/CU.
  __shared__ __align__(16) unsigned char LDS[100912];
  float* xb = (float*)LDS;
  unsigned int* z32 = (unsigned int*)LDS;
  unsigned short* z16 = (unsigned short*)LDS;
  f32x2* hf2 = (f32x2*)(LDS + 31744);
  unsigned short* a16 = (unsigned short*)(LDS + 31744);
  float* sw = (float*)(LDS + 90624);
  unsigned int* swu = (unsigned int*)(LDS + 90624);
  const f32x2* swf2 = (const f32x2*)(LDS + 90624);

  const int t = threadIdx.x;
  const int S0 = blockIdx.x*64;

  // ---- P0: stage x (coalesced float4) + precomputed small-weights image (coalesced) ----
  {
    const float4* src4 = (const float4*)(xg + (size_t)S0*65);
    float4* x4 = (float4*)xb;
    for (int i=t; i<1040; i+=1024) x4[i] = src4[i];   // 64*65 = 4160 floats
    if (t<8) xb[4160+t] = 0.f;   // proj over-read pad (zero-weight lanes)
    const unsigned int* swsrc = (const unsigned int*)(wpack + 181248);
    for (int idx=t; idx<2572; idx+=1024) swu[idx] = swsrc[idx];
  }
  __syncthreads();

  // ---- P1: block-diagonal projection -> h f32 pairs hf2[(j*5+p)*64+s] ----
  for (int L=t; L<7360; L+=1024){
    int s = L & 63, jp = L>>6;
    int j = jp/5, p = jp-5*j;
    int o0 = j*10 + 2*p;
    int roff = FOFF[j];
    float a0 = sw[o0*8+4], a1 = sw[o0*8+12];
    #pragma unroll
    for (int u=0;u<4;u++){
      float xv = xb[s*65 + roff + u];
      a0 += xv * sw[o0*8+u];
      a1 += xv * sw[o0*8+8+u];
    }
    f32x2 hv; hv.x = a0; hv.y = a1;
    hf2[jp*64 + s] = hv;
  }
  __syncthreads();

  // ---- P2: attention (16 waves; waves 0-6 take 2 rows each, waves 7-15 one row each) ----
  {
    const int s = t & 63;
    const int q = t >> 6;            // 0..15, exactly one wave per q
    if (q < 7){
      attn_chunk2(s, 2*q, 2, hf2, swf2, z32);     // rows 0..13
    } else {
      attn_chunk2(s, q+7, 1, hf2, swf2, z32);     // rows 14..22
    }
    __builtin_amdgcn_sched_barrier(0);
    if (q == 15){
      // lightest wave zeroes z pad cols 230..239 (K padded to 240 for layer1)
      for (int idx=s; idx<320; idx+=64){
        int ss = idx/5, pc = idx-5*ss;
        z32[ss*124 + 115+pc] = 0u;
      }
    }
  }
  __syncthreads();

  // ---- P3: MLP, 5 layers of MFMA, ping-pong LDS act buffers ----
  const bf16x8* wpk = (const bf16x8*)wpack;
  mlp_layer<15>(z16, 248, wpk,          b1, a16, t); __syncthreads();
  mlp_layer<11>(a16, 200, wpk + 5760,   b2, z16, t); __syncthreads();
  mlp_layer<11>(z16, 200, wpk + 9984,   b3, a16, t); __syncthreads();
  mlp_layer<11>(a16, 200, wpk + 14208,  b4, z16, t); __syncthreads();
  mlp_layer<11>(z16, 200, wpk + 18432,  b5, a16, t); __syncthreads();

  // ---- P4: heads (move[5] + mark[1]) ----
  if (t < 384){
    int s2 = t & 63, o = t>>6;
    const unsigned int* ar = (const unsigned int*)(a16 + s2*200);
    const unsigned int* wr = swu + 2080 + o*82;
    float acc = 0.f;
    for (int kp=0; kp<82; ++kp){
      unsigned int ua = ar[kp], uw = wr[kp];
      acc += bflo(ua)*bflo(uw) + bfhi(ua)*bfhi(uw);
    }
    acc += (o<5)? bmove[o] : bmark[0];
    if (o<5) out[(size_t)(S0+s2)*5 + o] = acc;
    else     out[(size_t)BATCH*5 + S0 + s2] = acc;
  }
}

extern "C" void kernel_launch(void* const* d_in, const int* in_sizes, int n_in,
                              void* d_out, int out_size, void* d_ws, size_t ws_size,
                              hipStream_t stream){
  (void)in_sizes; (void)n_in; (void)out_size; (void)ws_size;
  const float* x     = (const float*)d_in[0];
  const float* Wproj = (const float*)d_in[1];
  const float* bproj = (const float*)d_in[2];
  const float* Wq    = (const float*)d_in[3];
  const float* Wk    = (const float*)d_in[4];
  const float* Wv    = (const float*)d_in[5];
  const float* W1    = (const float*)d_in[6];
  const float* b1    = (const float*)d_in[7];
  const float* W2    = (const float*)d_in[8];
  const float* b2    = (const float*)d_in[9];
  const float* W3    = (const float*)d_in[10];
  const float* b3    = (const float*)d_in[11];
  const float* W4    = (const float*)d_in[12];
  const float* b4    = (const float*)d_in[13];
  const float* W5    = (const float*)d_in[14];
  const float* b5    = (const float*)d_in[15];
  const float* Wmove = (const float*)d_in[16];
  const float* bmove = (const float*)d_in[17];
  const float* Wmark = (const float*)d_in[18];
  const float* bmark = (const float*)d_in[19];
  unsigned short* wpack = (unsigned short*)d_ws;
  unsigned int* swimg = (unsigned int*)(wpack + 181248);   // after 22656*8 shorts

  prep_weights<<<89, 256, 0, stream>>>(W1, W2, W3, W4, W5, wpack);
  prep_small<<<11, 256, 0, stream>>>(Wproj, bproj, Wq, Wk, Wv, Wmove, Wmark, swimg);
  actor_main<<<2048, 1024, 0, stream>>>(x,
      b1, b2, b3, b4, b5, bmove, bmark, wpack, (float*)d_out);
}

// Round 10
// 265.311 us; speedup vs baseline: 1.2810x; 1.0321x over previous
//
#include <hip/hip_runtime.h>

#define BATCH 131072

typedef __attribute__((ext_vector_type(8))) __bf16 bf16x8;
typedef __attribute__((ext_vector_type(16))) float f32x16;
typedef __attribute__((ext_vector_type(2))) float f32x2;

__constant__ int FOFF[23] = {0,4,8,12,16,20,24,28,32,36,40,44,48,50,52,53,57,58,59,60,61,62,63};
__constant__ int FDIM[23] = {4,4,4,4,4,4,4,4,4,4,4,4,2,2,1,4,1,1,1,1,1,1,2};

__device__ __forceinline__ unsigned short f2bf(float f){
  unsigned int u = __float_as_uint(f);
  u += 0x7fffu + ((u>>16)&1u);   // RNE
  return (unsigned short)(u>>16);
}
__device__ __forceinline__ unsigned int packpair(float a, float b){
  return (unsigned int)f2bf(a) | ((unsigned int)f2bf(b)<<16);
}
__device__ __forceinline__ float bflo(unsigned int u){ return __uint_as_float(u<<16); }
__device__ __forceinline__ float bfhi(unsigned int u){ return __uint_as_float(u & 0xffff0000u); }

// ---------------- prep: pack W1..W5 into MFMA-B fragment-linear bf16 layout ----------------
__global__ void prep_weights(const float* __restrict__ W1, const float* __restrict__ W2,
    const float* __restrict__ W3, const float* __restrict__ W4, const float* __restrict__ W5,
    unsigned short* __restrict__ wpack){
  int idx = blockIdx.x*256 + threadIdx.x;
  if (idx >= 22656) return;
  const float* W; int rel; int Kd;
  if (idx < 5760){ W = W1; rel = idx; Kd = 230; }
  else {
    int r2 = idx - 5760;
    int li = r2 / 4224; rel = r2 - li*4224; Kd = 164;
    W = (li==0)?W2:((li==1)?W3:((li==2)?W4:W5));
  }
  int lane = rel & 63, rem = rel >> 6;
  int nt = rem % 6, ks = rem / 6;
  int n  = nt*32 + (lane&31);
  int k0 = ks*16 + ((lane>>5)<<3);
  unsigned int v[4];
  #pragma unroll
  for (int p=0;p<4;p++){
    int ka = k0 + 2*p, kb = ka+1;
    float fa = (ka<Kd && n<164) ? W[ka*164+n] : 0.f;
    float fb = (kb<Kd && n<164) ? W[kb*164+n] : 0.f;
    v[p] = packpair(fa, fb);
  }
  *(uint4*)(wpack + (size_t)idx*8) = make_uint4(v[0],v[1],v[2],v[3]);
}

// ---------------- prep: small-weights image ----------------
// word layout: [0,1840) proj packed f32 ([o][0..3]=w,[4]=bias,pad8); [1840,1960) M=WqWk^T/sqrt(10)
// [10][12] f32; [1960,2080) Wv [10][12] f32; [2080,3064) head weights f32 [6][164] (k-major).
__global__ void prep_small(const float* __restrict__ Wproj, const float* __restrict__ bproj,
    const float* __restrict__ Wq, const float* __restrict__ Wk, const float* __restrict__ Wv,
    const float* __restrict__ Wmove, const float* __restrict__ Wmark,
    unsigned int* __restrict__ swimg){
  int idx = blockIdx.x*256 + threadIdx.x;
  if (idx >= 3064) return;
  unsigned int outv;
  if (idx < 1840){
    int o = idx>>3, u = idx&7;
    int fi = o/10;
    float v = 0.f;
    if (u<4){ if (u < FDIM[fi]) v = Wproj[(FOFF[fi]+u)*230 + o]; }
    else if (u==4) v = bproj[o];
    outv = __float_as_uint(v);
  } else if (idx < 1960){
    int r = idx-1840, e = r/12, d = r-12*e;
    float v = 0.f;
    if (d<10){ float ssum=0.f;
      #pragma unroll
      for (int k2=0;k2<10;k2++) ssum += Wq[e*10+k2]*Wk[d*10+k2];
      v = ssum*0.31622776601683794f; }
    outv = __float_as_uint(v);
  } else if (idx < 2080){
    int r = idx-1960, e = r/12, d = r-12*e;
    outv = __float_as_uint((d<10)? Wv[e*10+d] : 0.f);
  } else {
    int r = idx-2080;            // 0..983
    int o = r/164, k = r-o*164;  // k 0..163
    outv = __float_as_uint((o<5)? Wmove[k*5+o] : Wmark[k]);
  }
  swimg[idx] = outv;
}

// ---------------- attention chunk: C (<=2) query rows, h as f32 pairs, pipelined j-loop ------
// All math f32x2 (v_pk_fma_f32). Manual software pipeline: hjA/hjB ping-pong prefetch so the
// ~120cyc LDS latency of key j+1 hides under key j's math. All array indices compile-time
// (rule #20). Runtime C + if(c<C) guards (R2 lesson: templated C merges live ranges -> spill).
__device__ __forceinline__ void attn_chunk2(int s, int ibase, int C,
    const f32x2* hf2, const f32x2* swf2, unsigned int* z32){
  // ---- g = h_i * M ----
  f32x2 g2[2][5];
  #pragma unroll
  for (int c=0;c<2;c++)
    #pragma unroll
    for (int p=0;p<5;p++) g2[c][p] = (f32x2){0.f,0.f};
  {
    f32x2 hi2[2][5];
    #pragma unroll
    for (int c=0;c<2;c++) if (c<C){
      #pragma unroll
      for (int p=0;p<5;p++) hi2[c][p] = hf2[((ibase+c)*5+p)*64 + s];
    }
    #pragma unroll
    for (int e=0;e<10;e++){
      f32x2 m2[5];
      #pragma unroll
      for (int p=0;p<5;p++) m2[p] = swf2[920 + e*6 + p];
      #pragma unroll
      for (int c=0;c<2;c++) if (c<C){
        float he = (e&1) ? hi2[c][e>>1].y : hi2[c][e>>1].x;
        #pragma unroll
        for (int p=0;p<5;p++) g2[c][p] += m2[p]*he;
      }
    }
  }
  // ---- single-pass unnormalized softmax over 23 keys (2-deep pipelined) ----
  f32x2 st2[2][5]; float tau[2];
  #pragma unroll
  for (int c=0;c<2;c++){
    tau[c]=0.f;
    #pragma unroll
    for (int p=0;p<5;p++) st2[c][p] = (f32x2){0.f,0.f};
  }
  f32x2 hjA[5], hjB[5];
  auto keystep = [&](f32x2 (&hj)[5]){
    #pragma unroll
    for (int c=0;c<2;c++) if (c<C){
      f32x2 l2 = g2[c][0]*hj[0];
      #pragma unroll
      for (int p=1;p<5;p++) l2 += g2[c][p]*hj[p];
      float e = __expf(l2.x + l2.y);
      tau[c] += e;
      #pragma unroll
      for (int p=0;p<5;p++) st2[c][p] += hj[p]*e;
    }
  };
  #pragma unroll
  for (int p=0;p<5;p++) hjA[p] = hf2[p*64 + s];                  // j=0
  for (int jj=0; jj<11; ++jj){
    #pragma unroll
    for (int p=0;p<5;p++) hjB[p] = hf2[((2*jj+1)*5+p)*64 + s];   // prefetch odd j
    keystep(hjA);                                                // compute even j
    #pragma unroll
    for (int p=0;p<5;p++) hjA[p] = hf2[((2*jj+2)*5+p)*64 + s];   // prefetch next even (<=22)
    keystep(hjB);                                                // compute odd j
  }
  keystep(hjA);                                                  // j=22
  #pragma unroll
  for (int c=0;c<2;c++) if (c<C){
    float inv = 1.f/tau[c];
    #pragma unroll
    for (int p=0;p<5;p++) st2[c][p] *= inv;
  }
  // ---- ctx = st * Wv ----
  f32x2 ct2[2][5];
  #pragma unroll
  for (int c=0;c<2;c++)
    #pragma unroll
    for (int p=0;p<5;p++) ct2[c][p] = (f32x2){0.f,0.f};
  #pragma unroll
  for (int e=0;e<10;e++){
    f32x2 wv2[5];
    #pragma unroll
    for (int p=0;p<5;p++) wv2[p] = swf2[980 + e*6 + p];
    #pragma unroll
    for (int c=0;c<2;c++) if (c<C){
      float se = (e&1) ? st2[c][e>>1].y : st2[c][e>>1].x;
      #pragma unroll
      for (int p=0;p<5;p++) ct2[c][p] += wv2[p]*se;
    }
  }
  // ---- residual + pack to z (v_cvt_pk_bf16_f32: 1 inst, RNE) ----
  #pragma unroll
  for (int c=0;c<2;c++) if (c<C){
    int i = ibase+c;
    #pragma unroll
    for (int p=0;p<5;p++){
      f32x2 h = hf2[(i*5+p)*64 + s];
      float z0 = h.x + ct2[c][p].x;
      float z1 = h.y + ct2[c][p].y;
      unsigned int r;
      asm volatile("v_cvt_pk_bf16_f32 %0, %1, %2" : "=v"(r) : "v"(z0), "v"(z1));
      z32[s*124 + i*5 + p] = r;
    }
  }
}

// ---------------- MFMA MLP inner: NT n-tiles for one 32-row M-tile ----------------
template<int KSTEPS, int NT>
__device__ __forceinline__ void mlp_tiles(const unsigned short* abase, const bf16x8* wb,
    const float* __restrict__ bias, unsigned short* out16, int nt0, int colb, int rowb){
  f32x16 acc[NT];
  #pragma unroll
  for (int nt=0; nt<NT; ++nt)
    #pragma unroll
    for (int r=0;r<16;r++) acc[nt][r]=0.f;
  #pragma unroll
  for (int ks=0; ks<KSTEPS; ++ks){
    bf16x8 a = *(const bf16x8*)(abase + ks*16);
    const bf16x8* wk = wb + ks*(6*64);
    #pragma unroll
    for (int nt=0; nt<NT; ++nt)
      acc[nt] = __builtin_amdgcn_mfma_f32_32x32x16_bf16(a, wk[nt*64], acc[nt], 0,0,0);
  }
  #pragma unroll
  for (int nt=0; nt<NT; ++nt){
    int n = (nt0+nt)*32 + colb;
    float b = (n<164) ? bias[n] : 0.f;
    #pragma unroll
    for (int r=0;r<16;r++){
      int row = rowb + (r&3) + 8*(r>>2);
      float v = fmaxf(acc[nt][r] + b, 0.f);
      out16[row*200 + n] = f2bf(v);
    }
  }
}

// 64 rows, 16 waves: 2 M-tiles x 6 N-tiles at NT=1 (12 active waves; MFMA ~2% of time)
template<int KSTEPS>
__device__ __forceinline__ void mlp_layer(const unsigned short* in16, int inPitch,
    const bf16x8* __restrict__ wp, const float* __restrict__ bias,
    unsigned short* out16, int t){
  const int lane = t & 63;
  const int w = t >> 6;      // 0..15
  const int mt = w & 1;      // 2 M-tiles of 32
  const int nt = w >> 1;     // 0..7; only 0..5 carry tiles (N 164->192)
  if (nt >= 6) return;
  const unsigned short* abase = in16 + (mt*32 + (lane&31))*inPitch + ((lane>>5)<<3);
  const int colb = lane&31;
  const int rowb = mt*32 + 4*(lane>>5);
  mlp_tiles<KSTEPS,1>(abase, wp + nt*64 + lane, bias, out16, nt, colb, rowb);
}

// ---------------- fused main kernel: 64 samples / 1024-thread workgroup ----------------
// 1 block/CU (16 waves) is the residency ceiling (unified regfile, R1/R4/R6/R7 evidence).
// Optimize per-wave latency instead: pipelined j-loop, f32 h, pk math, split-k heads.
__global__ __launch_bounds__(1024, 1) void actor_main(
    const float* __restrict__ xg,
    const float* __restrict__ b1, const float* __restrict__ b2, const float* __restrict__ b3,
    const float* __restrict__ b4, const float* __restrict__ b5,
    const float* __restrict__ bmove, const float* __restrict__ bmark,
    const unsigned short* __restrict__ wpack, float* __restrict__ out)
{
  // LDS: [0,31744) z-buffer (64 x pitch 248 bf16) / x-stage / P4-partials union;
  //      [31744,90624) h f32-pair SoA (23*5*64 f32x2) / act buffer union (64 x pitch 200 bf16);
  //      [90624,102880) small-weights image (3064 words). 1 workgroup/CU.
  __shared__ __align__(16) unsigned char LDS[102880];
  float* xb = (float*)LDS;
  unsigned int* z32 = (unsigned int*)LDS;
  unsigned short* z16 = (unsigned short*)LDS;
  f32x2* hf2 = (f32x2*)(LDS + 31744);
  unsigned short* a16 = (unsigned short*)(LDS + 31744);
  float* sw = (float*)(LDS + 90624);
  unsigned int* swu = (unsigned int*)(LDS + 90624);
  const f32x2* swf2 = (const f32x2*)(LDS + 90624);

  const int t = threadIdx.x;
  const int S0 = blockIdx.x*64;

  // ---- P0: stage x (coalesced float4) + small-weights image (coalesced) ----
  {
    const float4* src4 = (const float4*)(xg + (size_t)S0*65);
    float4* x4 = (float4*)LDS;
    for (int i=t; i<1040; i+=1024) x4[i] = src4[i];   // 64*65 = 4160 floats
    if (t<8) xb[4160+t] = 0.f;   // proj over-read pad (zero-weight lanes)
    const unsigned int* swsrc = (const unsigned int*)(wpack + 181248);
    for (int idx=t; idx<3064; idx+=1024) swu[idx] = swsrc[idx];
  }
  __syncthreads();

  // ---- P1: block-diagonal projection -> h f32 pairs hf2[(j*5+p)*64+s] ----
  for (int L=t; L<7360; L+=1024){
    int s = L & 63, jp = L>>6;
    int j = jp/5, p = jp-5*j;
    int o0 = j*10 + 2*p;
    int roff = FOFF[j];
    float a0 = sw[o0*8+4], a1 = sw[o0*8+12];
    #pragma unroll
    for (int u=0;u<4;u++){
      float xv = xb[s*65 + roff + u];
      a0 += xv * sw[o0*8+u];
      a1 += xv * sw[o0*8+8+u];
    }
    f32x2 hv; hv.x = a0; hv.y = a1;
    hf2[jp*64 + s] = hv;
  }
  __syncthreads();

  // ---- P2: attention (16 waves; waves 0-6 take 2 rows each, waves 7-15 one row each) ----
  {
    const int s = t & 63;
    const int q = t >> 6;            // 0..15, exactly one wave per q
    if (q < 7){
      attn_chunk2(s, 2*q, 2, hf2, swf2, z32);     // rows 0..13
    } else {
      attn_chunk2(s, q+7, 1, hf2, swf2, z32);     // rows 14..22
    }
    __builtin_amdgcn_sched_barrier(0);
    if (q == 15){
      // lightest wave zeroes z pad cols 230..239 (K padded to 240 for layer1)
      for (int idx=s; idx<320; idx+=64){
        int ss = idx/5, pc = idx-5*ss;
        z32[ss*124 + 115+pc] = 0u;
      }
    }
  }
  __syncthreads();

  // ---- P3: MLP, 5 layers of MFMA, ping-pong LDS act buffers (final acts in a16) ----
  const bf16x8* wpk = (const bf16x8*)wpack;
  mlp_layer<15>(z16, 248, wpk,          b1, a16, t); __syncthreads();
  mlp_layer<11>(a16, 200, wpk + 5760,   b2, z16, t); __syncthreads();
  mlp_layer<11>(z16, 200, wpk + 9984,   b3, a16, t); __syncthreads();
  mlp_layer<11>(a16, 200, wpk + 14208,  b4, z16, t); __syncthreads();
  mlp_layer<11>(z16, 200, wpk + 18432,  b5, a16, t); __syncthreads();

  // ---- P4: heads, split-k over 12 waves (uint4 act reads, f32 weights, pk_fma) ----
  {
    float* pb = (float*)LDS;   // z region is free now
    if (t < 768){
      int s2 = t & 63, r = t>>6;       // r 0..11
      int o = r>>1, half = r&1;
      const uint4* ar4 = (const uint4*)(a16 + s2*200);
      const f32x2* hw = swf2 + 1040 + o*82;   // word 2080 + o*164, as f32x2
      f32x2 acc2 = {0.f,0.f};
      if (half==0){
        #pragma unroll
        for (int q4=0;q4<10;q4++){           // kp 0..39
          uint4 v = ar4[q4];
          unsigned int wv[4] = {v.x,v.y,v.z,v.w};
          #pragma unroll
          for (int e=0;e<4;e++){
            f32x2 av; av.x = bflo(wv[e]); av.y = bfhi(wv[e]);
            acc2 += av * hw[q4*4+e];
          }
        }
      } else {
        #pragma unroll
        for (int q4=10;q4<20;q4++){          // kp 40..79
          uint4 v = ar4[q4];
          unsigned int wv[4] = {v.x,v.y,v.z,v.w};
          #pragma unroll
          for (int e=0;e<4;e++){
            f32x2 av; av.x = bflo(wv[e]); av.y = bfhi(wv[e]);
            acc2 += av * hw[q4*4+e];
          }
        }
        const unsigned int* ar = (const unsigned int*)(a16 + s2*200);
        #pragma unroll
        for (int kp=80;kp<82;kp++){
          unsigned int u = ar[kp];
          f32x2 av; av.x = bflo(u); av.y = bfhi(u);
          acc2 += av * hw[kp];
        }
      }
      pb[r*64 + s2] = acc2.x + acc2.y;
    }
    __syncthreads();
    if (t < 384){
      int s2 = t & 63, o = t>>6;
      float acc = pb[(2*o)*64 + s2] + pb[(2*o+1)*64 + s2];
      acc += (o<5)? bmove[o] : bmark[0];
      if (o<5) out[(size_t)(S0+s2)*5 + o] = acc;
      else     out[(size_t)BATCH*5 + S0 + s2] = acc;
    }
  }
}

extern "C" void kernel_launch(void* const* d_in, const int* in_sizes, int n_in,
                              void* d_out, int out_size, void* d_ws, size_t ws_size,
                              hipStream_t stream){
  (void)in_sizes; (void)n_in; (void)out_size; (void)ws_size;
  const float* x     = (const float*)d_in[0];
  const float* Wproj = (const float*)d_in[1];
  const float* bproj = (const float*)d_in[2];
  const float* Wq    = (const float*)d_in[3];
  const float* Wk    = (const float*)d_in[4];
  const float* Wv    = (const float*)d_in[5];
  const float* W1    = (const float*)d_in[6];
  const float* b1    = (const float*)d_in[7];
  const float* W2    = (const float*)d_in[8];
  const float* b2    = (const float*)d_in[9];
  const float* W3    = (const float*)d_in[10];
  const float* b3    = (const float*)d_in[11];
  const float* W4    = (const float*)d_in[12];
  const float* b4    = (const float*)d_in[13];
  const float* W5    = (const float*)d_in[14];
  const float* b5    = (const float*)d_in[15];
  const float* Wmove = (const float*)d_in[16];
  const float* bmove = (const float*)d_in[17];
  const float* Wmark = (const float*)d_in[18];
  const float* bmark = (const float*)d_in[19];
  unsigned short* wpack = (unsigned short*)d_ws;
  unsigned int* swimg = (unsigned int*)(wpack + 181248);   // after 22656*8 shorts

  prep_weights<<<89, 256, 0, stream>>>(W1, W2, W3, W4, W5, wpack);
  prep_small<<<12, 256, 0, stream>>>(Wproj, bproj, Wq, Wk, Wv, Wmove, Wmark, swimg);
  actor_main<<<2048, 1024, 0, stream>>>(x,
      b1, b2, b3, b4, b5, bmove, bmark, wpack, (float*)d_out);
}

// Round 11
// 258.244 us; speedup vs baseline: 1.3161x; 1.0274x over previous
//
#include <hip/hip_runtime.h>

#define BATCH 131072

typedef __attribute__((ext_vector_type(8))) __bf16 bf16x8;
typedef __attribute__((ext_vector_type(16))) float f32x16;
typedef __attribute__((ext_vector_type(2))) float f32x2;

__constant__ int FOFF[23] = {0,4,8,12,16,20,24,28,32,36,40,44,48,50,52,53,57,58,59,60,61,62,63};
__constant__ int FDIM[23] = {4,4,4,4,4,4,4,4,4,4,4,4,2,2,1,4,1,1,1,1,1,1,2};

__device__ __forceinline__ unsigned short f2bf(float f){
  unsigned int u = __float_as_uint(f);
  u += 0x7fffu + ((u>>16)&1u);   // RNE
  return (unsigned short)(u>>16);
}
__device__ __forceinline__ unsigned int packpair(float a, float b){
  return (unsigned int)f2bf(a) | ((unsigned int)f2bf(b)<<16);
}
__device__ __forceinline__ float bflo(unsigned int u){ return __uint_as_float(u<<16); }
__device__ __forceinline__ float bfhi(unsigned int u){ return __uint_as_float(u & 0xffff0000u); }

// ---------------- prep: pack W1..W5 into MFMA-B fragment-linear bf16 layout ----------------
__global__ void prep_weights(const float* __restrict__ W1, const float* __restrict__ W2,
    const float* __restrict__ W3, const float* __restrict__ W4, const float* __restrict__ W5,
    unsigned short* __restrict__ wpack){
  int idx = blockIdx.x*256 + threadIdx.x;
  if (idx >= 22656) return;
  const float* W; int rel; int Kd;
  if (idx < 5760){ W = W1; rel = idx; Kd = 230; }
  else {
    int r2 = idx - 5760;
    int li = r2 / 4224; rel = r2 - li*4224; Kd = 164;
    W = (li==0)?W2:((li==1)?W3:((li==2)?W4:W5));
  }
  int lane = rel & 63, rem = rel >> 6;
  int nt = rem % 6, ks = rem / 6;
  int n  = nt*32 + (lane&31);
  int k0 = ks*16 + ((lane>>5)<<3);
  unsigned int v[4];
  #pragma unroll
  for (int p=0;p<4;p++){
    int ka = k0 + 2*p, kb = ka+1;
    float fa = (ka<Kd && n<164) ? W[ka*164+n] : 0.f;
    float fb = (kb<Kd && n<164) ? W[kb*164+n] : 0.f;
    v[p] = packpair(fa, fb);
  }
  *(uint4*)(wpack + (size_t)idx*8) = make_uint4(v[0],v[1],v[2],v[3]);
}

// ---------------- prep: small-weights image ----------------
// word layout: [0,1840) proj packed f32 ([o][0..3]=w,[4]=bias,pad8); [1840,1960) M=WqWk^T/sqrt(10)
// [10][12] f32; [1960,2080) Wv [10][12] f32; [2080,3064) head weights f32 [6][164] (k-major).
__global__ void prep_small(const float* __restrict__ Wproj, const float* __restrict__ bproj,
    const float* __restrict__ Wq, const float* __restrict__ Wk, const float* __restrict__ Wv,
    const float* __restrict__ Wmove, const float* __restrict__ Wmark,
    unsigned int* __restrict__ swimg){
  int idx = blockIdx.x*256 + threadIdx.x;
  if (idx >= 3064) return;
  unsigned int outv;
  if (idx < 1840){
    int o = idx>>3, u = idx&7;
    int fi = o/10;
    float v = 0.f;
    if (u<4){ if (u < FDIM[fi]) v = Wproj[(FOFF[fi]+u)*230 + o]; }
    else if (u==4) v = bproj[o];
    outv = __float_as_uint(v);
  } else if (idx < 1960){
    int r = idx-1840, e = r/12, d = r-12*e;
    float v = 0.f;
    if (d<10){ float ssum=0.f;
      #pragma unroll
      for (int k2=0;k2<10;k2++) ssum += Wq[e*10+k2]*Wk[d*10+k2];
      v = ssum*0.31622776601683794f; }
    outv = __float_as_uint(v);
  } else if (idx < 2080){
    int r = idx-1960, e = r/12, d = r-12*e;
    outv = __float_as_uint((d<10)? Wv[e*10+d] : 0.f);
  } else {
    int r = idx-2080;            // 0..983
    int o = r/164, k = r-o*164;  // k 0..163
    outv = __float_as_uint((o<5)? Wmove[k*5+o] : Wmark[k]);
  }
  swimg[idx] = outv;
}

// ---------------- attention chunk: C (<=2) query rows, h f32 pairs (pitch 32), pipelined ------
// All math f32x2 (v_pk_fma_f32); 2-deep hjA/hjB prefetch hides ds_read_b64 latency.
// Runtime C + if(c<C) guards (R2 lesson: templated C merges live ranges -> spill).
__device__ __forceinline__ void attn_chunk2(int s, int ibase, int C,
    const f32x2* hf2, const f32x2* swf2, unsigned int* z32){
  // ---- g = h_i * M ----
  f32x2 g2[2][5];
  #pragma unroll
  for (int c=0;c<2;c++)
    #pragma unroll
    for (int p=0;p<5;p++) g2[c][p] = (f32x2){0.f,0.f};
  {
    f32x2 hi2[2][5];
    #pragma unroll
    for (int c=0;c<2;c++) if (c<C){
      #pragma unroll
      for (int p=0;p<5;p++) hi2[c][p] = hf2[((ibase+c)*5+p)*32 + s];
    }
    #pragma unroll
    for (int e=0;e<10;e++){
      f32x2 m2[5];
      #pragma unroll
      for (int p=0;p<5;p++) m2[p] = swf2[e*6 + p];
      #pragma unroll
      for (int c=0;c<2;c++) if (c<C){
        float he = (e&1) ? hi2[c][e>>1].y : hi2[c][e>>1].x;
        #pragma unroll
        for (int p=0;p<5;p++) g2[c][p] += m2[p]*he;
      }
    }
  }
  // ---- single-pass unnormalized softmax over 23 keys (2-deep pipelined) ----
  f32x2 st2[2][5]; float tau[2];
  #pragma unroll
  for (int c=0;c<2;c++){
    tau[c]=0.f;
    #pragma unroll
    for (int p=0;p<5;p++) st2[c][p] = (f32x2){0.f,0.f};
  }
  f32x2 hjA[5], hjB[5];
  auto keystep = [&](f32x2 (&hj)[5]){
    #pragma unroll
    for (int c=0;c<2;c++) if (c<C){
      f32x2 l2 = g2[c][0]*hj[0];
      #pragma unroll
      for (int p=1;p<5;p++) l2 += g2[c][p]*hj[p];
      float e = __expf(l2.x + l2.y);
      tau[c] += e;
      #pragma unroll
      for (int p=0;p<5;p++) st2[c][p] += hj[p]*e;
    }
  };
  #pragma unroll
  for (int p=0;p<5;p++) hjA[p] = hf2[p*32 + s];                  // j=0
  for (int jj=0; jj<11; ++jj){
    #pragma unroll
    for (int p=0;p<5;p++) hjB[p] = hf2[((2*jj+1)*5+p)*32 + s];   // prefetch odd j
    keystep(hjA);                                                // compute even j
    #pragma unroll
    for (int p=0;p<5;p++) hjA[p] = hf2[((2*jj+2)*5+p)*32 + s];   // prefetch next even (<=22)
    keystep(hjB);                                                // compute odd j
  }
  keystep(hjA);                                                  // j=22
  #pragma unroll
  for (int c=0;c<2;c++) if (c<C){
    float inv = 1.f/tau[c];
    #pragma unroll
    for (int p=0;p<5;p++) st2[c][p] *= inv;
  }
  // ---- ctx = st * Wv ----
  f32x2 ct2[2][5];
  #pragma unroll
  for (int c=0;c<2;c++)
    #pragma unroll
    for (int p=0;p<5;p++) ct2[c][p] = (f32x2){0.f,0.f};
  #pragma unroll
  for (int e=0;e<10;e++){
    f32x2 wv2[5];
    #pragma unroll
    for (int p=0;p<5;p++) wv2[p] = swf2[60 + e*6 + p];
    #pragma unroll
    for (int c=0;c<2;c++) if (c<C){
      float se = (e&1) ? st2[c][e>>1].y : st2[c][e>>1].x;
      #pragma unroll
      for (int p=0;p<5;p++) ct2[c][p] += wv2[p]*se;
    }
  }
  // ---- residual + pack to z (v_cvt_pk_bf16_f32: 1 inst, RNE) ----
  #pragma unroll
  for (int c=0;c<2;c++) if (c<C){
    int i = ibase+c;
    #pragma unroll
    for (int p=0;p<5;p++){
      f32x2 h = hf2[(i*5+p)*32 + s];
      float z0 = h.x + ct2[c][p].x;
      float z1 = h.y + ct2[c][p].y;
      unsigned int r;
      asm volatile("v_cvt_pk_bf16_f32 %0, %1, %2" : "=v"(r) : "v"(z0), "v"(z1));
      z32[s*124 + i*5 + p] = r;
    }
  }
}

// ---------------- MFMA MLP: 32 rows, 6 active waves, 1 N-tile each (N 164->192) --------------
template<int KSTEPS>
__device__ __forceinline__ void mlp_layer(const unsigned short* in16, int inPitch,
    const bf16x8* __restrict__ wp, const float* __restrict__ bias,
    unsigned short* out16, int t){
  const int lane = t & 63;
  const int nt = t >> 6;     // 0..7; only 0..5 carry tiles
  if (nt >= 6) return;
  const unsigned short* abase = in16 + (lane&31)*inPitch + ((lane>>5)<<3);
  const bf16x8* wb = wp + nt*64 + lane;
  f32x16 acc;
  #pragma unroll
  for (int r=0;r<16;r++) acc[r]=0.f;
  #pragma unroll
  for (int ks=0; ks<KSTEPS; ++ks){
    bf16x8 a = *(const bf16x8*)(abase + ks*16);
    acc = __builtin_amdgcn_mfma_f32_32x32x16_bf16(a, wb[ks*(6*64)], acc, 0,0,0);
  }
  const int colb = lane&31;
  const int rowb = 4*(lane>>5);
  int n = nt*32 + colb;
  float b = (n<164) ? bias[n] : 0.f;
  #pragma unroll
  for (int r=0;r<16;r++){
    int row = rowb + (r&3) + 8*(r>>2);
    float v = fmaxf(acc[r] + b, 0.f);
    out16[row*200 + n] = f2bf(v);
  }
}

// ---------------- fused main kernel: 32 samples / 512-thread workgroup, 3 blocks/CU ----------
// Residency decode (R0-R10): waves/SIMD = floor(512 / (archVGPR + 16 AGPR)) at BLOCK granularity.
// 1024-thr blocks need arch<=48 for 2 blocks (impossible: body needs ~52). 512-thr blocks need
// only arch<=69 for 3 blocks (24 waves/CU) -- body is 52. LDS trimmed to 50,208 B (proj weights
// union'd into the x/z region, die after P1) so 3x50,208 = 150,624 <= 160 KiB.
__global__ __launch_bounds__(512, 3) void actor_main(
    const float* __restrict__ xg,
    const float* __restrict__ b1, const float* __restrict__ b2, const float* __restrict__ b3,
    const float* __restrict__ b4, const float* __restrict__ b5,
    const float* __restrict__ bmove, const float* __restrict__ bmark,
    const unsigned short* __restrict__ wpack, float* __restrict__ out)
{
  // LDS: [0,15872) z-buffer (32 x pitch 248 bf16) / {x-stage [0,8352) + proj weights
  //      [8352,15712)} union / P4-partials union;
  //      [15872,45312) h f32-pair SoA (23*5*32 f32x2) / act buffer union (32 x pitch 200 bf16);
  //      [45312,50208) persistent small weights: M [0,120), Wv [120,240), heads [240,1224) words.
  __shared__ __align__(16) unsigned char LDS[50208];
  float* xb = (float*)LDS;
  unsigned int* xw = (unsigned int*)LDS;
  unsigned int* z32 = (unsigned int*)LDS;
  unsigned short* z16 = (unsigned short*)LDS;
  f32x2* hf2 = (f32x2*)(LDS + 15872);
  unsigned short* a16 = (unsigned short*)(LDS + 15872);
  float* swp = (float*)(LDS + 45312);
  const f32x2* swf2 = (const f32x2*)(LDS + 45312);

  const int t = threadIdx.x;
  const int S0 = blockIdx.x*32;

  // ---- P0: stage x (coalesced float4) + proj into x-region + persistent small weights ----
  {
    const float4* src4 = (const float4*)(xg + (size_t)S0*65);
    float4* x4 = (float4*)LDS;
    for (int i=t; i<520; i+=512) x4[i] = src4[i];   // 32*65 = 2080 floats
    if (t<8) xb[2080+t] = 0.f;   // proj over-read pad (zero-weight lanes)
    const unsigned int* swsrc = (const unsigned int*)(wpack + 181248);
    for (int idx=t; idx<1840; idx+=512) xw[2088+idx] = swsrc[idx];        // proj words
    for (int idx=t; idx<1224; idx+=512)
      ((unsigned int*)swp)[idx] = swsrc[1840+idx];                        // M/Wv/heads
  }
  __syncthreads();

  // ---- P1: block-diagonal projection -> h f32 pairs hf2[(j*5+p)*32+s] ----
  const float* pw = xb + 2088;
  for (int L=t; L<3680; L+=512){
    int s = L & 31, jp = L>>5;
    int j = jp/5, p = jp-5*j;
    int o0 = j*10 + 2*p;
    int roff = FOFF[j];
    float a0 = pw[o0*8+4], a1 = pw[o0*8+12];
    #pragma unroll
    for (int u=0;u<4;u++){
      float xv = xb[s*65 + roff + u];
      a0 += xv * pw[o0*8+u];
      a1 += xv * pw[o0*8+8+u];
    }
    f32x2 hv; hv.x = a0; hv.y = a1;
    hf2[jp*32 + s] = hv;
  }
  __syncthreads();

  // ---- P2: attention (16 thread-groups of 32; groups 0-6 two rows, 7-15 one row) ----
  {
    const int s = t & 31;
    const int q = t >> 5;            // 0..15 (half-wave granules; one mixed wave is fine:
                                     // guards predicate per-thread)
    if (q < 7){
      attn_chunk2(s, 2*q, 2, hf2, swf2, z32);     // rows 0..13
    } else {
      attn_chunk2(s, q+7, 1, hf2, swf2, z32);     // rows 14..22
    }
    __builtin_amdgcn_sched_barrier(0);
    // zero z pad cols 230..239 (K padded to 240 for layer1); disjoint addresses, no race
    for (int idx=t; idx<160; idx+=512){
      int ss = idx/5, pc = idx-5*ss;
      z32[ss*124 + 115+pc] = 0u;
    }
  }
  __syncthreads();

  // ---- P3: MLP, 5 layers of MFMA, ping-pong LDS act buffers (final acts in a16) ----
  const bf16x8* wpk = (const bf16x8*)wpack;
  mlp_layer<15>(z16, 248, wpk,          b1, a16, t); __syncthreads();
  mlp_layer<11>(a16, 200, wpk + 5760,   b2, z16, t); __syncthreads();
  mlp_layer<11>(z16, 200, wpk + 9984,   b3, a16, t); __syncthreads();
  mlp_layer<11>(a16, 200, wpk + 14208,  b4, z16, t); __syncthreads();
  mlp_layer<11>(z16, 200, wpk + 18432,  b5, a16, t); __syncthreads();

  // ---- P4: heads, split-k over 12 groups (uint4 act reads, f32 weights, pk_fma) ----
  {
    float* pb = (float*)LDS;   // z region is free now
    if (t < 384){
      int s2 = t & 31, r = t>>5;       // r 0..11
      int o = r>>1, half = r&1;
      const uint4* ar4 = (const uint4*)(a16 + s2*200);
      const f32x2* hw = swf2 + 120 + o*82;   // persistent word 240 + o*164, as f32x2
      f32x2 acc2 = {0.f,0.f};
      if (half==0){
        #pragma unroll
        for (int q4=0;q4<10;q4++){           // kp 0..39
          uint4 v = ar4[q4];
          unsigned int wv[4] = {v.x,v.y,v.z,v.w};
          #pragma unroll
          for (int e=0;e<4;e++){
            f32x2 av; av.x = bflo(wv[e]); av.y = bfhi(wv[e]);
            acc2 += av * hw[q4*4+e];
          }
        }
      } else {
        #pragma unroll
        for (int q4=10;q4<20;q4++){          // kp 40..79
          uint4 v = ar4[q4];
          unsigned int wv[4] = {v.x,v.y,v.z,v.w};
          #pragma unroll
          for (int e=0;e<4;e++){
            f32x2 av; av.x = bflo(wv[e]); av.y = bfhi(wv[e]);
            acc2 += av * hw[q4*4+e];
          }
        }
        const unsigned int* ar = (const unsigned int*)(a16 + s2*200);
        #pragma unroll
        for (int kp=80;kp<82;kp++){
          unsigned int u = ar[kp];
          f32x2 av; av.x = bflo(u); av.y = bfhi(u);
          acc2 += av * hw[kp];
        }
      }
      pb[r*32 + s2] = acc2.x + acc2.y;
    }
    __syncthreads();
    if (t < 192){
      int s2 = t & 31, o = t>>5;
      float acc = pb[(2*o)*32 + s2] + pb[(2*o+1)*32 + s2];
      acc += (o<5)? bmove[o] : bmark[0];
      if (o<5) out[(size_t)(S0+s2)*5 + o] = acc;
      else     out[(size_t)BATCH*5 + S0 + s2] = acc;
    }
  }
}

extern "C" void kernel_launch(void* const* d_in, const int* in_sizes, int n_in,
                              void* d_out, int out_size, void* d_ws, size_t ws_size,
                              hipStream_t stream){
  (void)in_sizes; (void)n_in; (void)out_size; (void)ws_size;
  const float* x     = (const float*)d_in[0];
  const float* Wproj = (const float*)d_in[1];
  const float* bproj = (const float*)d_in[2];
  const float* Wq    = (const float*)d_in[3];
  const float* Wk    = (const float*)d_in[4];
  const float* Wv    = (const float*)d_in[5];
  const float* W1    = (const float*)d_in[6];
  const float* b1    = (const float*)d_in[7];
  const float* W2    = (const float*)d_in[8];
  const float* b2    = (const float*)d_in[9];
  const float* W3    = (const float*)d_in[10];
  const float* b3    = (const float*)d_in[11];
  const float* W4    = (const float*)d_in[12];
  const float* b4    = (const float*)d_in[13];
  const float* W5    = (const float*)d_in[14];
  const float* b5    = (const float*)d_in[15];
  const float* Wmove = (const float*)d_in[16];
  const float* bmove = (const float*)d_in[17];
  const float* Wmark = (const float*)d_in[18];
  const float* bmark = (const float*)d_in[19];
  unsigned short* wpack = (unsigned short*)d_ws;
  unsigned int* swimg = (unsigned int*)(wpack + 181248);   // after 22656*8 shorts

  prep_weights<<<89, 256, 0, stream>>>(W1, W2, W3, W4, W5, wpack);
  prep_small<<<12, 256, 0, stream>>>(Wproj, bproj, Wq, Wk, Wv, Wmove, Wmark, swimg);
  actor_main<<<4096, 512, 0, stream>>>(x,
      b1, b2, b3, b4, b5, bmove, bmark, wpack, (float*)d_out);
}

// Round 12
// 248.954 us; speedup vs baseline: 1.3652x; 1.0373x over previous
//
#include <hip/hip_runtime.h>

#define BATCH 131072

typedef __attribute__((ext_vector_type(8))) __bf16 bf16x8;
typedef __attribute__((ext_vector_type(16))) float f32x16;
typedef __attribute__((ext_vector_type(2))) float f32x2;

__constant__ int FOFF[23] = {0,4,8,12,16,20,24,28,32,36,40,44,48,50,52,53,57,58,59,60,61,62,63};
__constant__ int FDIM[23] = {4,4,4,4,4,4,4,4,4,4,4,4,2,2,1,4,1,1,1,1,1,1,2};

__device__ __forceinline__ unsigned short f2bf(float f){
  unsigned int u = __float_as_uint(f);
  u += 0x7fffu + ((u>>16)&1u);   // RNE
  return (unsigned short)(u>>16);
}
__device__ __forceinline__ unsigned int packpair(float a, float b){
  return (unsigned int)f2bf(a) | ((unsigned int)f2bf(b)<<16);
}
__device__ __forceinline__ float bflo(unsigned int u){ return __uint_as_float(u<<16); }
__device__ __forceinline__ float bfhi(unsigned int u){ return __uint_as_float(u & 0xffff0000u); }

// ---------------- prep: pack W1..W5 into MFMA-B fragment-linear bf16 layout ----------------
__global__ void prep_weights(const float* __restrict__ W1, const float* __restrict__ W2,
    const float* __restrict__ W3, const float* __restrict__ W4, const float* __restrict__ W5,
    unsigned short* __restrict__ wpack){
  int idx = blockIdx.x*256 + threadIdx.x;
  if (idx >= 22656) return;
  const float* W; int rel; int Kd;
  if (idx < 5760){ W = W1; rel = idx; Kd = 230; }
  else {
    int r2 = idx - 5760;
    int li = r2 / 4224; rel = r2 - li*4224; Kd = 164;
    W = (li==0)?W2:((li==1)?W3:((li==2)?W4:W5));
  }
  int lane = rel & 63, rem = rel >> 6;
  int nt = rem % 6, ks = rem / 6;
  int n  = nt*32 + (lane&31);
  int k0 = ks*16 + ((lane>>5)<<3);
  unsigned int v[4];
  #pragma unroll
  for (int p=0;p<4;p++){
    int ka = k0 + 2*p, kb = ka+1;
    float fa = (ka<Kd && n<164) ? W[ka*164+n] : 0.f;
    float fb = (kb<Kd && n<164) ? W[kb*164+n] : 0.f;
    v[p] = packpair(fa, fb);
  }
  *(uint4*)(wpack + (size_t)idx*8) = make_uint4(v[0],v[1],v[2],v[3]);
}

// ---------------- prep: small-weights image ----------------
// word layout: [0,1380) proj PAIR-packed: pair p (outputs 2p,2p+1) uses 12 words:
//   [2u]=w_even[u], [2u+1]=w_odd[u] (u=0..3), [8]=b_even, [9]=b_odd, [10]=roff (raw u32), [11]=0.
// [1380,1500) M=WqWk^T/sqrt(10) [10][12] f32; [1500,1620) Wv [10][12] f32;
// [1620,2604) head weights f32 [6][164] (k-major).
__global__ void prep_small(const float* __restrict__ Wproj, const float* __restrict__ bproj,
    const float* __restrict__ Wq, const float* __restrict__ Wk, const float* __restrict__ Wv,
    const float* __restrict__ Wmove, const float* __restrict__ Wmark,
    unsigned int* __restrict__ swimg){
  int idx = blockIdx.x*256 + threadIdx.x;
  if (idx >= 2604) return;
  unsigned int outv;
  if (idx < 1380){
    int p = idx/12, rem = idx - p*12;
    int fi = p/5;                    // 5 output-pairs per feature
    int roff = FOFF[fi], dims = FDIM[fi];
    if (rem < 8){
      int u = rem>>1, odd = rem&1;
      float v = (u < dims) ? Wproj[(roff+u)*230 + 2*p+odd] : 0.f;
      outv = __float_as_uint(v);
    } else if (rem < 10){
      outv = __float_as_uint(bproj[2*p + (rem-8)]);
    } else if (rem == 10){
      outv = (unsigned int)roff;
    } else outv = 0u;
  } else if (idx < 1500){
    int r = idx-1380, e = r/12, d = r-12*e;
    float v = 0.f;
    if (d<10){ float ssum=0.f;
      #pragma unroll
      for (int k2=0;k2<10;k2++) ssum += Wq[e*10+k2]*Wk[d*10+k2];
      v = ssum*0.31622776601683794f; }
    outv = __float_as_uint(v);
  } else if (idx < 1620){
    int r = idx-1500, e = r/12, d = r-12*e;
    outv = __float_as_uint((d<10)? Wv[e*10+d] : 0.f);
  } else {
    int r = idx-1620;            // 0..983
    int o = r/164, k = r-o*164;  // k 0..163
    outv = __float_as_uint((o<5)? Wmove[k*5+o] : Wmark[k]);
  }
  swimg[idx] = outv;
}

// ---------------- attention chunk: C (<=2) query rows, h f32 pairs (pitch 32), pipelined ------
// All math f32x2 (v_pk_fma_f32); 2-deep hjA/hjB prefetch hides ds_read_b64 latency.
// Runtime C + if(c<C) guards (R2 lesson: templated C merges live ranges -> spill).
__device__ __forceinline__ void attn_chunk2(int s, int ibase, int C,
    const f32x2* hf2, const f32x2* swf2, unsigned int* z32){
  // ---- g = h_i * M ----
  f32x2 g2[2][5];
  #pragma unroll
  for (int c=0;c<2;c++)
    #pragma unroll
    for (int p=0;p<5;p++) g2[c][p] = (f32x2){0.f,0.f};
  {
    f32x2 hi2[2][5];
    #pragma unroll
    for (int c=0;c<2;c++) if (c<C){
      #pragma unroll
      for (int p=0;p<5;p++) hi2[c][p] = hf2[((ibase+c)*5+p)*32 + s];
    }
    #pragma unroll
    for (int e=0;e<10;e++){
      f32x2 m2[5];
      #pragma unroll
      for (int p=0;p<5;p++) m2[p] = swf2[e*6 + p];
      #pragma unroll
      for (int c=0;c<2;c++) if (c<C){
        float he = (e&1) ? hi2[c][e>>1].y : hi2[c][e>>1].x;
        #pragma unroll
        for (int p=0;p<5;p++) g2[c][p] += m2[p]*he;
      }
    }
  }
  // ---- single-pass unnormalized softmax over 23 keys (2-deep pipelined) ----
  f32x2 st2[2][5]; float tau[2];
  #pragma unroll
  for (int c=0;c<2;c++){
    tau[c]=0.f;
    #pragma unroll
    for (int p=0;p<5;p++) st2[c][p] = (f32x2){0.f,0.f};
  }
  f32x2 hjA[5], hjB[5];
  auto keystep = [&](f32x2 (&hj)[5]){
    #pragma unroll
    for (int c=0;c<2;c++) if (c<C){
      f32x2 l2 = g2[c][0]*hj[0];
      #pragma unroll
      for (int p=1;p<5;p++) l2 += g2[c][p]*hj[p];
      float e = __expf(l2.x + l2.y);
      tau[c] += e;
      #pragma unroll
      for (int p=0;p<5;p++) st2[c][p] += hj[p]*e;
    }
  };
  #pragma unroll
  for (int p=0;p<5;p++) hjA[p] = hf2[p*32 + s];                  // j=0
  for (int jj=0; jj<11; ++jj){
    #pragma unroll
    for (int p=0;p<5;p++) hjB[p] = hf2[((2*jj+1)*5+p)*32 + s];   // prefetch odd j
    keystep(hjA);                                                // compute even j
    #pragma unroll
    for (int p=0;p<5;p++) hjA[p] = hf2[((2*jj+2)*5+p)*32 + s];   // prefetch next even (<=22)
    keystep(hjB);                                                // compute odd j
  }
  keystep(hjA);                                                  // j=22
  #pragma unroll
  for (int c=0;c<2;c++) if (c<C){
    float inv = 1.f/tau[c];
    #pragma unroll
    for (int p=0;p<5;p++) st2[c][p] *= inv;
  }
  // ---- ctx = st * Wv ----
  f32x2 ct2[2][5];
  #pragma unroll
  for (int c=0;c<2;c++)
    #pragma unroll
    for (int p=0;p<5;p++) ct2[c][p] = (f32x2){0.f,0.f};
  #pragma unroll
  for (int e=0;e<10;e++){
    f32x2 wv2[5];
    #pragma unroll
    for (int p=0;p<5;p++) wv2[p] = swf2[60 + e*6 + p];
    #pragma unroll
    for (int c=0;c<2;c++) if (c<C){
      float se = (e&1) ? st2[c][e>>1].y : st2[c][e>>1].x;
      #pragma unroll
      for (int p=0;p<5;p++) ct2[c][p] += wv2[p]*se;
    }
  }
  // ---- residual + pack to z (v_cvt_pk_bf16_f32: 1 inst, RNE) ----
  #pragma unroll
  for (int c=0;c<2;c++) if (c<C){
    int i = ibase+c;
    #pragma unroll
    for (int p=0;p<5;p++){
      f32x2 h = hf2[(i*5+p)*32 + s];
      float z0 = h.x + ct2[c][p].x;
      float z1 = h.y + ct2[c][p].y;
      unsigned int r;
      asm volatile("v_cvt_pk_bf16_f32 %0, %1, %2" : "=v"(r) : "v"(z0), "v"(z1));
      z32[s*124 + i*5 + p] = r;
    }
  }
}

// ---------------- MFMA MLP: 32 rows, 6 active waves, 1 N-tile each (N 164->192) --------------
template<int KSTEPS>
__device__ __forceinline__ void mlp_layer(const unsigned short* in16, int inPitch,
    const bf16x8* __restrict__ wp, const float* __restrict__ bias,
    unsigned short* out16, int t){
  const int lane = t & 63;
  const int nt = t >> 6;     // 0..7; only 0..5 carry tiles
  if (nt >= 6) return;
  const unsigned short* abase = in16 + (lane&31)*inPitch + ((lane>>5)<<3);
  const bf16x8* wb = wp + nt*64 + lane;
  f32x16 acc;
  #pragma unroll
  for (int r=0;r<16;r++) acc[r]=0.f;
  #pragma unroll
  for (int ks=0; ks<KSTEPS; ++ks){
    bf16x8 a = *(const bf16x8*)(abase + ks*16);
    acc = __builtin_amdgcn_mfma_f32_32x32x16_bf16(a, wb[ks*(6*64)], acc, 0,0,0);
  }
  const int colb = lane&31;
  const int rowb = 4*(lane>>5);
  int n = nt*32 + colb;
  float b = (n<164) ? bias[n] : 0.f;
  #pragma unroll
  for (int r=0;r<16;r++){
    int row = rowb + (r&3) + 8*(r>>2);
    float v = fmaxf(acc[r] + b, 0.f);
    out16[row*200 + n] = f2bf(v);
  }
}

// ---------------- fused main kernel: 32 samples / 512-thread workgroup, 3 blocks/CU ----------
// Residency (R0-R11): waves/SIMD = floor(512/(archVGPR+16 AGPR)) at block granularity; 512-thr
// blocks at arch<=69 give 3 blocks/CU. P2 branch is WAVE-uniform (q<8 boundary): R11's q<7 put
// C=2 and C=1 in the same wave -> serialized both bodies (2.7x critical path).
__global__ __launch_bounds__(512, 3) void actor_main(
    const float* __restrict__ xg,
    const float* __restrict__ b1, const float* __restrict__ b2, const float* __restrict__ b3,
    const float* __restrict__ b4, const float* __restrict__ b5,
    const float* __restrict__ bmove, const float* __restrict__ bmark,
    const unsigned short* __restrict__ wpack, float* __restrict__ out)
{
  // LDS: [0,15872) z-buffer (32 x pitch 248 bf16) / {x-stage [0,8352) + proj pairs
  //      [8352,13872)} union / P4-partials union;
  //      [15872,45312) h f32-pair SoA (23*5*32 f32x2) / act buffer union (32 x pitch 200 bf16);
  //      [45312,50208) persistent small weights: M [0,120), Wv [120,240), heads [240,1224) words.
  __shared__ __align__(16) unsigned char LDS[50208];
  float* xb = (float*)LDS;
  unsigned int* xw = (unsigned int*)LDS;
  unsigned int* z32 = (unsigned int*)LDS;
  unsigned short* z16 = (unsigned short*)LDS;
  f32x2* hf2 = (f32x2*)(LDS + 15872);
  unsigned short* a16 = (unsigned short*)(LDS + 15872);
  float* swp = (float*)(LDS + 45312);
  const f32x2* swf2 = (const f32x2*)(LDS + 45312);

  const int t = threadIdx.x;
  const int S0 = blockIdx.x*32;

  // ---- P0: stage x (coalesced float4) + proj pairs into x-region + persistent weights ----
  {
    const float4* src4 = (const float4*)(xg + (size_t)S0*65);
    float4* x4 = (float4*)LDS;
    for (int i=t; i<520; i+=512) x4[i] = src4[i];   // 32*65 = 2080 floats
    if (t<8) xb[2080+t] = 0.f;   // proj over-read pad (zero-weight lanes)
    const unsigned int* swsrc = (const unsigned int*)(wpack + 181248);
    for (int idx=t; idx<1380; idx+=512) xw[2088+idx] = swsrc[idx];        // proj pair words
    for (int idx=t; idx<1224; idx+=512)
      ((unsigned int*)swp)[idx] = swsrc[1380+idx];                        // M/Wv/heads
  }
  __syncthreads();

  // ---- P1: projection via pk_fma pairs -> h f32 pairs hf2[k*32+s], k=0..114 ----
  {
    const f32x2* pw2 = (const f32x2*)(xb + 2088);
    const unsigned int* pwu = (const unsigned int*)(xb + 2088);
    for (int L=t; L<3680; L+=512){
      int s = L & 31, k = L>>5;
      int roff = (int)pwu[k*12 + 10];
      f32x2 acc = pw2[k*6 + 4];          // bias pair
      #pragma unroll
      for (int u=0;u<4;u++){
        float xv = xb[s*65 + roff + u];
        acc += pw2[k*6 + u] * xv;
      }
      hf2[k*32 + s] = acc;
    }
  }
  __syncthreads();

  // ---- P2: attention, WAVE-UNIFORM branch: waves 0-3 C=2 (rows 0-15), waves 4-7 C=1 ----
  {
    const int s = t & 31;
    const int q = t >> 5;            // 0..15; branch boundary at q=8 = wave boundary
    if (q < 8){
      attn_chunk2(s, 2*q, 2, hf2, swf2, z32);        // rows 0..15
    } else {
      int row = (q==15) ? 22 : q+8;                  // rows 16..22; group 15 dups row 22
      attn_chunk2(s, row, 1, hf2, swf2, z32);        // (identical recompute: benign race)
    }
    __builtin_amdgcn_sched_barrier(0);
    // zero z pad cols 230..239 (K padded to 240 for layer1); disjoint addresses, no race
    for (int idx=t; idx<160; idx+=512){
      int ss = idx/5, pc = idx-5*ss;
      z32[ss*124 + 115+pc] = 0u;
    }
  }
  __syncthreads();

  // ---- P3: MLP, 5 layers of MFMA, ping-pong LDS act buffers (final acts in a16) ----
  const bf16x8* wpk = (const bf16x8*)wpack;
  mlp_layer<15>(z16, 248, wpk,          b1, a16, t); __syncthreads();
  mlp_layer<11>(a16, 200, wpk + 5760,   b2, z16, t); __syncthreads();
  mlp_layer<11>(z16, 200, wpk + 9984,   b3, a16, t); __syncthreads();
  mlp_layer<11>(a16, 200, wpk + 14208,  b4, z16, t); __syncthreads();
  mlp_layer<11>(z16, 200, wpk + 18432,  b5, a16, t); __syncthreads();

  // ---- P4: heads, split-k over 12 groups (uint4 act reads, f32 weights, pk_fma) ----
  {
    float* pb = (float*)LDS;   // z region is free now
    if (t < 384){
      int s2 = t & 31, r = t>>5;       // r 0..11
      int o = r>>1, half = r&1;
      const uint4* ar4 = (const uint4*)(a16 + s2*200);
      const f32x2* hw = swf2 + 120 + o*82;   // persistent word 240 + o*164, as f32x2
      f32x2 acc2 = {0.f,0.f};
      if (half==0){
        #pragma unroll
        for (int q4=0;q4<10;q4++){           // kp 0..39
          uint4 v = ar4[q4];
          unsigned int wv[4] = {v.x,v.y,v.z,v.w};
          #pragma unroll
          for (int e=0;e<4;e++){
            f32x2 av; av.x = bflo(wv[e]); av.y = bfhi(wv[e]);
            acc2 += av * hw[q4*4+e];
          }
        }
      } else {
        #pragma unroll
        for (int q4=10;q4<20;q4++){          // kp 40..79
          uint4 v = ar4[q4];
          unsigned int wv[4] = {v.x,v.y,v.z,v.w};
          #pragma unroll
          for (int e=0;e<4;e++){
            f32x2 av; av.x = bflo(wv[e]); av.y = bfhi(wv[e]);
            acc2 += av * hw[q4*4+e];
          }
        }
        const unsigned int* ar = (const unsigned int*)(a16 + s2*200);
        #pragma unroll
        for (int kp=80;kp<82;kp++){
          unsigned int u = ar[kp];
          f32x2 av; av.x = bflo(u); av.y = bfhi(u);
          acc2 += av * hw[kp];
        }
      }
      pb[r*32 + s2] = acc2.x + acc2.y;
    }
    __syncthreads();
    if (t < 192){
      int s2 = t & 31, o = t>>5;
      float acc = pb[(2*o)*32 + s2] + pb[(2*o+1)*32 + s2];
      acc += (o<5)? bmove[o] : bmark[0];
      if (o<5) out[(size_t)(S0+s2)*5 + o] = acc;
      else     out[(size_t)BATCH*5 + S0 + s2] = acc;
    }
  }
}

extern "C" void kernel_launch(void* const* d_in, const int* in_sizes, int n_in,
                              void* d_out, int out_size, void* d_ws, size_t ws_size,
                              hipStream_t stream){
  (void)in_sizes; (void)n_in; (void)out_size; (void)ws_size;
  const float* x     = (const float*)d_in[0];
  const float* Wproj = (const float*)d_in[1];
  const float* bproj = (const float*)d_in[2];
  const float* Wq    = (const float*)d_in[3];
  const float* Wk    = (const float*)d_in[4];
  const float* Wv    = (const float*)d_in[5];
  const float* W1    = (const float*)d_in[6];
  const float* b1    = (const float*)d_in[7];
  const float* W2    = (const float*)d_in[8];
  const float* b2    = (const float*)d_in[9];
  const float* W3    = (const float*)d_in[10];
  const float* b3    = (const float*)d_in[11];
  const float* W4    = (const float*)d_in[12];
  const float* b4    = (const float*)d_in[13];
  const float* W5    = (const float*)d_in[14];
  const float* b5    = (const float*)d_in[15];
  const float* Wmove = (const float*)d_in[16];
  const float* bmove = (const float*)d_in[17];
  const float* Wmark = (const float*)d_in[18];
  const float* bmark = (const float*)d_in[19];
  unsigned short* wpack = (unsigned short*)d_ws;
  unsigned int* swimg = (unsigned int*)(wpack + 181248);   // after 22656*8 shorts

  prep_weights<<<89, 256, 0, stream>>>(W1, W2, W3, W4, W5, wpack);
  prep_small<<<11, 256, 0, stream>>>(Wproj, bproj, Wq, Wk, Wv, Wmove, Wmark, swimg);
  actor_main<<<4096, 512, 0, stream>>>(x,
      b1, b2, b3, b4, b5, bmove, bmark, wpack, (float*)d_out);
}